// Round 12
// baseline (275.698 us; speedup 1.0000x reference)
//
#include <hip/hip_runtime.h>
#include <hip/hip_bf16.h>

// Dims
#define BATCH 16
#define SEQ 1024
#define NROWS (BATCH*SEQ)          // 16384 tokens
#define IN_DIM 768
#define DM 128
#define DIP 644
#define DI 256
#define CDIM 384
#define DST 64
#define NH 4
#define HD 64
#define CHUNK 64
#define NCHUNK (SEQ/CHUNK)         // 16

// bf16 weight area offsets (in shorts)
#define WB_FC1   0          // [128][768]
#define WB_IN    98304      // [2][644][128]
#define WB_OUT   263168     // [2][128][256]
#define WB_FC2   328704     // [128][128]
#define WB_TOTAL 345088

typedef __attribute__((ext_vector_type(8))) short short8;
typedef __attribute__((ext_vector_type(4))) float float4v;

// f32 -> bf16 (RNE) as raw short
__device__ __forceinline__ short f2b(float f) {
    unsigned u = __builtin_bit_cast(unsigned, f);
    u += 0x7fffu + ((u >> 16) & 1u);
    return (short)(u >> 16);
}
__device__ __forceinline__ float s2f(short s) {
    unsigned u = ((unsigned)(unsigned short)s) << 16;
    return __builtin_bit_cast(float, u);
}
__device__ __forceinline__ short8 pack8f(float4 a, float4 b) {
    short8 r;
    r[0] = f2b(a.x); r[1] = f2b(a.y); r[2] = f2b(a.z); r[3] = f2b(a.w);
    r[4] = f2b(b.x); r[5] = f2b(b.y); r[6] = f2b(b.z); r[7] = f2b(b.w);
    return r;
}
__device__ __forceinline__ float silu(float a) { return a / (1.f + expf(-a)); }

// ---------------- weight prep: convert + transpose to bf16 ----------------
__global__ void prep_weights(const float* __restrict__ fc1_W, const float* __restrict__ in_W,
                             const float* __restrict__ out_W, const float* __restrict__ fc2_W1,
                             short* __restrict__ wb) {
    int idx = blockIdx.x * 256 + threadIdx.x;
    if (idx < 98304) {                       // fc1_Wt[n][k] <- fc1_W[k][n]
        int n = idx / 768, k = idx % 768;
        wb[WB_FC1 + idx] = f2b(fc1_W[k * 128 + n]);
        return;
    }
    idx -= 98304;
    if (idx < 2 * 82432) {                   // in_Wt[l][n][k] <- in_W[l][k][n]
        int l = idx / 82432, r = idx % 82432;
        int n = r / 128, k = r % 128;
        wb[WB_IN + idx] = f2b(in_W[(size_t)l * 82432 + k * 644 + n]);
        return;
    }
    idx -= 164864;
    if (idx < 2 * 32768) {                   // out_Wt[l][n][k] <- out_W[l][k][n]
        int l = idx / 32768, r = idx % 32768;
        int n = r / 256, k = r % 256;
        wb[WB_OUT + idx] = f2b(out_W[(size_t)l * 32768 + k * 128 + n]);
        return;
    }
    idx -= 65536;
    if (idx < 16384) {                       // fc2_W1t[n][k] <- fc2_W1[k][n]
        int n = idx / 128, k = idx % 128;
        wb[WB_FC2 + idx] = f2b(fc2_W1[k * 128 + n]);
    }
}

// ============================================================
// 512-thread MFMA GEMM macros (inproj only now)
// ============================================================
#define GEMM_PROLOGUE() \
    int tid = threadIdx.x; \
    int lane = tid & 63; \
    int m = lane & 15; \
    int kq = (lane >> 4) * 8; \
    int w = tid >> 6; \
    int mrow = (w & 3) * 16; \
    int ngrp = w >> 2; \
    int a_off = (mrow + m) * 72 + kq; \
    int b_off = (ngrp * 64 + m) * 72 + kq; \
    int ar = tid >> 3; \
    int ak = (tid & 7) * 8; \
    (void)ar; (void)ak; \
    float4v acc[4]; \
    acc[0] = (float4v)0.f; acc[1] = (float4v)0.f; acc[2] = (float4v)0.f; acc[3] = (float4v)0.f;

#define GEMM_COMPUTE_TILE() \
    { \
        short8 a0 = *reinterpret_cast<const short8*>(&As[a_off]); \
        short8 a1 = *reinterpret_cast<const short8*>(&As[a_off + 32]); \
        _Pragma("unroll") \
        for (int nt = 0; nt < 4; nt++) { \
            short8 b0 = *reinterpret_cast<const short8*>(&Bt[b_off + nt * 16 * 72]); \
            short8 b1 = *reinterpret_cast<const short8*>(&Bt[b_off + nt * 16 * 72 + 32]); \
            acc[nt] = __builtin_amdgcn_mfma_f32_16x16x32_bf16(a0, b0, acc[nt], 0, 0, 0); \
            acc[nt] = __builtin_amdgcn_mfma_f32_16x16x32_bf16(a1, b1, acc[nt], 0, 0, 0); \
        } \
    }

// ---------------- fc1 (MFMA, M=32, 256thr) + PE + register-LN -> h f32, hnb bf16 ----------------
__global__ __launch_bounds__(256) void fc1_mfma(const float* __restrict__ x,
                                                const short* __restrict__ wt,
                                                const float* __restrict__ bias,
                                                const float* __restrict__ lnw0,
                                                const float* __restrict__ lnb0,
                                                float* __restrict__ h,
                                                short* __restrict__ hnb) {
    __shared__ short As[32 * 72];
    __shared__ short Bt[128 * 72];
    __shared__ float ps1[32][2], ps2[32][2];
    int tid = threadIdx.x;
    int lane = tid & 63;
    int m = lane & 15;
    int quad = lane >> 4;
    int kq = quad * 8;
    int w = tid >> 6;          // 0..3
    int mrow = (w & 1) * 16;
    int ngrp = w >> 1;
    int ar = tid >> 3;         // 0..31
    int ak = (tid & 7) * 8;
    int row0 = blockIdx.x * 32;
    float4v acc[4];
    acc[0] = (float4v)0.f; acc[1] = (float4v)0.f; acc[2] = (float4v)0.f; acc[3] = (float4v)0.f;
    for (int kt = 0; kt < 12; kt++) {
        int k0 = kt * 64;
        if (kt) __syncthreads();
        {
            const float* src = x + (size_t)(row0 + ar) * IN_DIM + k0 + ak;
            float4 v0 = *(const float4*)src;
            float4 v1 = *(const float4*)(src + 4);
            *reinterpret_cast<short8*>(&As[ar * 72 + ak]) = pack8f(v0, v1);
        }
        #pragma unroll
        for (int i = 0; i < 4; i++) {
            int idx = tid + i * 256;
            int n = idx >> 3, kk = (idx & 7) * 8;
            *reinterpret_cast<short8*>(&Bt[n * 72 + kk]) =
                *reinterpret_cast<const short8*>(&wt[n * 768 + k0 + kk]);
        }
        __syncthreads();
        short8 a0 = *reinterpret_cast<const short8*>(&As[(mrow + m) * 72 + kq]);
        short8 a1 = *reinterpret_cast<const short8*>(&As[(mrow + m) * 72 + kq + 32]);
        #pragma unroll
        for (int nt = 0; nt < 4; nt++) {
            int bo = (ngrp * 64 + nt * 16 + m) * 72 + kq;
            short8 b0 = *reinterpret_cast<const short8*>(&Bt[bo]);
            short8 b1 = *reinterpret_cast<const short8*>(&Bt[bo + 32]);
            acc[nt] = __builtin_amdgcn_mfma_f32_16x16x32_bf16(a0, b0, acc[nt], 0, 0, 0);
            acc[nt] = __builtin_amdgcn_mfma_f32_16x16x32_bf16(a1, b1, acc[nt], 0, 0, 0);
        }
    }
    // epilogue: bias + PE in registers, LN stats via shuffle + tiny LDS exchange
    float val[4][4];
    float s1r[4] = {0.f,0.f,0.f,0.f}, s2r[4] = {0.f,0.f,0.f,0.f};
    #pragma unroll
    for (int nt = 0; nt < 4; nt++) {
        int col = ngrp * 64 + nt * 16 + m;
        float bv = bias[col];
        float div = expf(-(float)(col & ~1) * 0.071955784f);
        #pragma unroll
        for (int r = 0; r < 4; r++) {
            int row = row0 + mrow + quad * 4 + r;
            int t = row & (SEQ - 1);
            float arg = (float)t * div;
            float pe = (col & 1) ? cosf(arg) : sinf(arg);
            float v = acc[nt][r] + bv + pe;
            val[nt][r] = v;
            s1r[r] += v; s2r[r] += v * v;
        }
    }
    #pragma unroll
    for (int o = 1; o < 16; o <<= 1) {
        #pragma unroll
        for (int r = 0; r < 4; r++) {
            s1r[r] += __shfl_xor(s1r[r], o);
            s2r[r] += __shfl_xor(s2r[r], o);
        }
    }
    if (m == 0) {
        #pragma unroll
        for (int r = 0; r < 4; r++) {
            ps1[mrow + quad * 4 + r][ngrp] = s1r[r];
            ps2[mrow + quad * 4 + r][ngrp] = s2r[r];
        }
    }
    __syncthreads();
    #pragma unroll
    for (int r = 0; r < 4; r++) {
        int rl = mrow + quad * 4 + r;
        float s1 = ps1[rl][0] + ps1[rl][1];
        float s2 = ps2[rl][0] + ps2[rl][1];
        float mu = s1 * (1.f / 128.f);
        float rs = rsqrtf(s2 * (1.f / 128.f) - mu * mu + 1e-5f);
        int row = row0 + rl;
        #pragma unroll
        for (int nt = 0; nt < 4; nt++) {
            int col = ngrp * 64 + nt * 16 + m;
            float v = val[nt][r];
            h[(size_t)row * DM + col] = v;
            hnb[(size_t)row * DM + col] = f2b((v - mu) * rs * lnw0[col] + lnb0[col]);
        }
    }
}

// ---------------- in_proj: z->bf16 zb, xBC->bf16, dt->softplus->dtb ----------------
__global__ __launch_bounds__(512) void inproj_mfma(const short* __restrict__ hnb,
                                                   const short* __restrict__ wb,
                                                   short* __restrict__ zb,
                                                   short* __restrict__ xbc,
                                                   float* __restrict__ dtb,
                                                   const float* __restrict__ dt_bias, int layer) {
    __shared__ short As[64 * 72];
    __shared__ short Bt[128 * 72];
    GEMM_PROLOGUE();
    int row0 = blockIdx.x * 64;
    int ncol0 = blockIdx.y * 128;
    const short* wt = wb + WB_IN + (size_t)layer * 82432;
    for (int kt = 0; kt < 2; kt++) {
        int k0 = kt * 64;
        if (kt) __syncthreads();
        *reinterpret_cast<short8*>(&As[ar * 72 + ak]) =
            *reinterpret_cast<const short8*>(&hnb[(size_t)(row0 + ar) * DM + k0 + ak]);
        #pragma unroll
        for (int i = 0; i < 2; i++) {
            int idx = tid + i * 512;
            int n = idx >> 3, kk = (idx & 7) * 8;
            int col = ncol0 + n;
            short8 bv = (short8)0;
            if (col < DIP) bv = *reinterpret_cast<const short8*>(&wt[col * 128 + k0 + kk]);
            *reinterpret_cast<short8*>(&Bt[n * 72 + kk]) = bv;
        }
        __syncthreads();
        GEMM_COMPUTE_TILE();
    }
    #pragma unroll
    for (int nt = 0; nt < 4; nt++) {
        int col = ncol0 + ngrp * 64 + nt * 16 + m;
        if (col < DI) {
            #pragma unroll
            for (int r = 0; r < 4; r++) {
                int row = row0 + mrow + (lane >> 4) * 4 + r;
                zb[(size_t)row * DI + col] = f2b(acc[nt][r]);
            }
        } else if (col < DI + CDIM) {
            #pragma unroll
            for (int r = 0; r < 4; r++) {
                int row = row0 + mrow + (lane >> 4) * 4 + r;
                xbc[(size_t)row * CDIM + (col - DI)] = f2b(acc[nt][r]);
            }
        } else if (col < DIP) {
            int hh = col - DI - CDIM;
            float db = dt_bias[layer * NH + hh];
            #pragma unroll
            for (int r = 0; r < 4; r++) {
                int row = row0 + mrow + (lane >> 4) * 4 + r;
                float raw = acc[nt][r] + db;
                float dt = (raw > 20.f) ? raw : log1pf(expf(raw));
                dtb[(size_t)row * NH + hh] = dt;
            }
        }
    }
}

// ---------------- causal conv(4) + SiLU, 4 tokens/block (bf16 in/out) ----------------
__global__ void conv_kernel(const short* __restrict__ xbc,
                            const float* __restrict__ convw, const float* __restrict__ convb,
                            short* __restrict__ xcb, int layer) {
    int c = threadIdx.x;            // 384
    int row0 = blockIdx.x * 4;
    int l0 = row0 & (SEQ - 1);
    const float* cw = convw + (size_t)layer * 4 * CDIM;
    float w0 = cw[c], w1 = cw[CDIM + c], w2 = cw[2 * CDIM + c], w3 = cw[3 * CDIM + c];
    float bb = convb[layer * CDIM + c];
    float v[7];
    #pragma unroll
    for (int i = 0; i < 7; i++) {
        int rr = row0 + i - 3;
        v[i] = (l0 + i - 3 >= 0) ? s2f(xbc[(size_t)rr * CDIM + c]) : 0.f;
    }
    #pragma unroll
    for (int j = 0; j < 4; j++) {
        float acc = bb + w0 * v[j] + w1 * v[j + 1] + w2 * v[j + 2] + w3 * v[j + 3];
        xcb[(size_t)(row0 + j) * CDIM + c] = f2b(silu(acc));
    }
}

// ---------------- chunk A (MFMA): S[p][n] -> bf16 ----------------
__global__ __launch_bounds__(256) void chunk_state_mfma(const short* __restrict__ xcb,
                                                        const float* __restrict__ dtb,
                                                        const float* __restrict__ A_log,
                                                        short* __restrict__ Slocb,
                                                        float* __restrict__ decay, int layer) {
    __shared__ short XTw[64 * 72];   // [p][t]
    __shared__ short BT[64 * 72];    // [n][t]
    __shared__ float wst[64];
    int bid = blockIdx.x;
    int c  = bid & (NCHUNK - 1);
    int hh = (bid >> 4) & (NH - 1);
    int b  = bid >> 6;
    int tid = threadIdx.x;
    int row0 = b * SEQ + c * CHUNK;
    float A = -expf(A_log[layer * NH + hh]);

    if (tid < CHUNK) {
        float dtv = dtb[(size_t)(row0 + tid) * NH + hh];
        float l = dtv * A;
        #pragma unroll
        for (int o = 1; o < 64; o <<= 1) { float v = __shfl_up(l, o); if (tid >= o) l += v; }
        float Ltot = __shfl(l, 63);
        wst[tid] = expf(Ltot - l) * dtv;
        if (tid == 63) decay[bid] = expf(Ltot);
    }
    __syncthreads();
    {
        int p = tid & 63;
        int tb0 = tid >> 6;
        #pragma unroll
        for (int i = 0; i < 2; i++) {
            int t0 = (tb0 + i * 4) * 8;
            short8 xv, bv;
            #pragma unroll
            for (int j = 0; j < 8; j++) {
                int t = t0 + j;
                const short* xr = xcb + (size_t)(row0 + t) * CDIM;
                xv[j] = f2b(s2f(xr[hh * HD + p]) * wst[t]);
                bv[j] = xr[DI + p];
            }
            *reinterpret_cast<short8*>(&XTw[p * 72 + t0]) = xv;
            *reinterpret_cast<short8*>(&BT[p * 72 + t0]) = bv;
        }
    }
    __syncthreads();

    int lane = tid & 63;
    int m = lane & 15;
    int kq = (lane >> 4) * 8;
    int w = tid >> 6;
    int a_off = (w * 16 + m) * 72 + kq;
    float4v acc[4];
    acc[0] = (float4v)0.f; acc[1] = (float4v)0.f; acc[2] = (float4v)0.f; acc[3] = (float4v)0.f;
    short8 a0 = *reinterpret_cast<const short8*>(&XTw[a_off]);
    short8 a1 = *reinterpret_cast<const short8*>(&XTw[a_off + 32]);
    #pragma unroll
    for (int nt = 0; nt < 4; nt++) {
        int bo = (nt * 16 + m) * 72 + kq;
        short8 b0 = *reinterpret_cast<const short8*>(&BT[bo]);
        short8 b1 = *reinterpret_cast<const short8*>(&BT[bo + 32]);
        acc[nt] = __builtin_amdgcn_mfma_f32_16x16x32_bf16(a0, b0, acc[nt], 0, 0, 0);
        acc[nt] = __builtin_amdgcn_mfma_f32_16x16x32_bf16(a1, b1, acc[nt], 0, 0, 0);
    }
    short* Sp = Slocb + (size_t)bid * (HD * DST);
    int tq = (lane >> 4) * 4;
    #pragma unroll
    for (int nt = 0; nt < 4; nt++) {
        #pragma unroll
        for (int r = 0; r < 4; r++) {
            int p = w * 16 + tq + r;
            int n = nt * 16 + m;
            Sp[p * DST + n] = f2b(acc[nt][r]);   // [p][n] bf16
        }
    }
}

// ---------------- chunk B: inter-chunk recurrence (bf16 io, f32 accum) ----------------
__global__ void chunk_scan_kernel(const short* __restrict__ Slocb, const float* __restrict__ decay,
                                  short* __restrict__ hstrb) {
    int bh = blockIdx.x;
    int tid = threadIdx.x;
    float hreg[16];
    #pragma unroll
    for (int k = 0; k < 16; k++) hreg[k] = 0.f;
    for (int c = 0; c < NCHUNK; c++) {
        size_t base = ((size_t)bh * NCHUNK + c) * (HD * DST) + tid * 16;
        float d = decay[bh * NCHUNK + c];
        short8 s0 = *reinterpret_cast<const short8*>(&Slocb[base]);
        short8 s1 = *reinterpret_cast<const short8*>(&Slocb[base + 8]);
        short8 h0, h1;
        #pragma unroll
        for (int k = 0; k < 8; k++) { h0[k] = f2b(hreg[k]); h1[k] = f2b(hreg[8 + k]); }
        *reinterpret_cast<short8*>(&hstrb[base]) = h0;
        *reinterpret_cast<short8*>(&hstrb[base + 8]) = h1;
        #pragma unroll
        for (int k = 0; k < 8; k++) {
            hreg[k]     = d * hreg[k]     + s2f(s0[k]);
            hreg[8 + k] = d * hreg[8 + k] + s2f(s1[k]);
        }
    }
}

// ---------------- chunk C (MFMA): outputs -> y bf16 ----------------
__global__ __launch_bounds__(256) void chunk_out_mfma(const short* __restrict__ xcb,
                                                      const float* __restrict__ dtb,
                                                      const float* __restrict__ A_log,
                                                      const float* __restrict__ Dpw,
                                                      const short* __restrict__ hstrb,
                                                      short* __restrict__ ybb, int layer) {
    __shared__ short Cb[64 * 72];    // [t][n]
    __shared__ short Bb[64 * 72];    // [s][n], later M[t][s]
    __shared__ short XT[64 * 72];    // [p][t]
    __shared__ short HT[64 * 72];    // [p][n]
    __shared__ float Ls[64], dts[64];
    int bid = blockIdx.x;
    int c  = bid & (NCHUNK - 1);
    int hh = (bid >> 4) & (NH - 1);
    int b  = bid >> 6;
    int tid = threadIdx.x;
    int row0 = b * SEQ + c * CHUNK;
    float A = -expf(A_log[layer * NH + hh]);
    float Dph = Dpw[layer * NH + hh];

    if (tid < CHUNK) {
        float dtv = dtb[(size_t)(row0 + tid) * NH + hh];
        float l = dtv * A;
        #pragma unroll
        for (int o = 1; o < 64; o <<= 1) { float v = __shfl_up(l, o); if (tid >= o) l += v; }
        Ls[tid] = l;
        dts[tid] = dtv;
    }
    {
        int p = tid & 63;
        int tb0 = tid >> 6;
        #pragma unroll
        for (int i = 0; i < 2; i++) {
            int t0 = (tb0 + i * 4) * 8;
            short8 xv;
            #pragma unroll
            for (int j = 0; j < 8; j++)
                xv[j] = xcb[(size_t)(row0 + t0 + j) * CDIM + hh * HD + p];
            *reinterpret_cast<short8*>(&XT[p * 72 + t0]) = xv;
        }
    }
    #pragma unroll
    for (int i = 0; i < 2; i++) {   // Bb, Cb: direct bf16 copies
        int idx = tid + i * 256;
        int t = idx >> 3, cb = (idx & 7) * 8;
        const short* xr = xcb + (size_t)(row0 + t) * CDIM;
        *reinterpret_cast<short8*>(&Bb[t * 72 + cb]) =
            *reinterpret_cast<const short8*>(&xr[DI + cb]);
        *reinterpret_cast<short8*>(&Cb[t * 72 + cb]) =
            *reinterpret_cast<const short8*>(&xr[DI + DST + cb]);
    }
    {
        const short* hs = hstrb + (size_t)bid * (HD * DST);   // [p][n]
        #pragma unroll
        for (int i = 0; i < 2; i++) {
            int idx = tid + i * 256;
            int pp = idx >> 3, nb = (idx & 7) * 8;
            *reinterpret_cast<short8*>(&HT[pp * 72 + nb]) =
                *reinterpret_cast<const short8*>(&hs[pp * 64 + nb]);
        }
    }
    __syncthreads();

    int lane = tid & 63;
    int m = lane & 15;
    int kq = (lane >> 4) * 8;
    int w = tid >> 6;
    int tq = (lane >> 4) * 4;
    int a_off = (w * 16 + m) * 72 + kq;

    short8 ca0 = *reinterpret_cast<const short8*>(&Cb[a_off]);
    short8 ca1 = *reinterpret_cast<const short8*>(&Cb[a_off + 32]);

    float4v g[4], ir[4];
    #pragma unroll
    for (int i = 0; i < 4; i++) { g[i] = (float4v)0.f; ir[i] = (float4v)0.f; }
    #pragma unroll
    for (int st = 0; st < 4; st++) {
        int bo = (st * 16 + m) * 72 + kq;
        short8 b0 = *reinterpret_cast<const short8*>(&Bb[bo]);
        short8 b1 = *reinterpret_cast<const short8*>(&Bb[bo + 32]);
        g[st] = __builtin_amdgcn_mfma_f32_16x16x32_bf16(ca0, b0, g[st], 0, 0, 0);
        g[st] = __builtin_amdgcn_mfma_f32_16x16x32_bf16(ca1, b1, g[st], 0, 0, 0);
        short8 h0 = *reinterpret_cast<const short8*>(&HT[bo]);
        short8 h1 = *reinterpret_cast<const short8*>(&HT[bo + 32]);
        ir[st] = __builtin_amdgcn_mfma_f32_16x16x32_bf16(ca0, h0, ir[st], 0, 0, 0);
        ir[st] = __builtin_amdgcn_mfma_f32_16x16x32_bf16(ca1, h1, ir[st], 0, 0, 0);
    }
    __syncthreads();
    #pragma unroll
    for (int st = 0; st < 4; st++) {
        #pragma unroll
        for (int r = 0; r < 4; r++) {
            int t = w * 16 + tq + r;
            int s = st * 16 + m;
            float mv = 0.f;
            if (s <= t) mv = g[st][r] * expf(Ls[t] - Ls[s]) * dts[s];
            Bb[t * 72 + s] = f2b(mv);
        }
    }
    __syncthreads();
    float4v yi[4];
    #pragma unroll
    for (int i = 0; i < 4; i++) yi[i] = (float4v)0.f;
    short8 ma0 = *reinterpret_cast<const short8*>(&Bb[a_off]);
    short8 ma1 = *reinterpret_cast<const short8*>(&Bb[a_off + 32]);
    #pragma unroll
    for (int pt = 0; pt < 4; pt++) {
        int bo = (pt * 16 + m) * 72 + kq;
        short8 x0 = *reinterpret_cast<const short8*>(&XT[bo]);
        short8 x1 = *reinterpret_cast<const short8*>(&XT[bo + 32]);
        yi[pt] = __builtin_amdgcn_mfma_f32_16x16x32_bf16(ma0, x0, yi[pt], 0, 0, 0);
        yi[pt] = __builtin_amdgcn_mfma_f32_16x16x32_bf16(ma1, x1, yi[pt], 0, 0, 0);
    }
    #pragma unroll
    for (int r = 0; r < 4; r++) {
        int t = w * 16 + tq + r;
        float et = expf(Ls[t]);
        short* yr = ybb + (size_t)(row0 + t) * DI + hh * HD;
        #pragma unroll
        for (int pt = 0; pt < 4; pt++) {
            int p = pt * 16 + m;
            float xv = s2f(XT[p * 72 + t]);
            yr[p] = f2b(yi[pt][r] + et * ir[pt][r] + Dph * xv);
        }
    }
}

// ---------------- out_proj (M=32, 256thr) + gate/RMSNorm + residual + next-layer LN ----------------
__global__ __launch_bounds__(256) void outproj_gate_mfma(const short* __restrict__ ybb,
                                                         const short* __restrict__ zb,
                                                         const float* __restrict__ rmsw,
                                                         const short* __restrict__ wb,
                                                         const float* __restrict__ lnw2,
                                                         const float* __restrict__ lnb2,
                                                         float* __restrict__ h,
                                                         short* __restrict__ hnb,
                                                         int layer, int write_hn) {
    __shared__ short As[32 * 72];
    __shared__ short Bt[128 * 72];
    __shared__ float rs_s[32];
    __shared__ float ps1[32][2], ps2[32][2];
    int tid = threadIdx.x;
    int lane = tid & 63;
    int m = lane & 15;
    int quad = lane >> 4;
    int kq = quad * 8;
    int w = tid >> 6;
    int mrow = (w & 1) * 16;
    int ngrp = w >> 1;
    int ar = tid >> 3;
    int ak = (tid & 7) * 8;
    int row0 = blockIdx.x * 32;
    const short* wt = wb + WB_OUT + (size_t)layer * 32768;
    {   // RMS stats on v = y*silu(z): 8 threads/row (r=0..31), 32 cols each
        int r = tid >> 3, j = tid & 7;
        const short8* yr = (const short8*)(ybb + (size_t)(row0 + r) * DI + j * 32);
        const short8* zr = (const short8*)(zb + (size_t)(row0 + r) * DI + j * 32);
        float s2 = 0.f;
        #pragma unroll
        for (int i = 0; i < 4; i++) {
            short8 yv = yr[i];
            short8 zv = zr[i];
            #pragma unroll
            for (int q = 0; q < 8; q++) {
                float v = s2f(yv[q]) * silu(s2f(zv[q]));
                s2 += v * v;
            }
        }
        #pragma unroll
        for (int o = 1; o < 8; o <<= 1) s2 += __shfl_xor(s2, o);
        if (j == 0) rs_s[r] = rsqrtf(s2 * (1.f / 256.f) + 1e-5f);
    }
    __syncthreads();
    float4v acc[4];
    acc[0] = (float4v)0.f; acc[1] = (float4v)0.f; acc[2] = (float4v)0.f; acc[3] = (float4v)0.f;
    for (int kt = 0; kt < 4; kt++) {
        int k0 = kt * 64;
        if (kt) __syncthreads();
        {
            int k = k0 + ak;
            short8 yv = *(const short8*)(ybb + (size_t)(row0 + ar) * DI + k);
            short8 zv = *(const short8*)(zb + (size_t)(row0 + ar) * DI + k);
            float4 w0 = *(const float4*)(rmsw + layer * DI + k);
            float4 w1 = *(const float4*)(rmsw + layer * DI + k + 4);
            float rs = rs_s[ar];
            short8 av;
            av[0] = f2b(s2f(yv[0]) * silu(s2f(zv[0])) * rs * w0.x);
            av[1] = f2b(s2f(yv[1]) * silu(s2f(zv[1])) * rs * w0.y);
            av[2] = f2b(s2f(yv[2]) * silu(s2f(zv[2])) * rs * w0.z);
            av[3] = f2b(s2f(yv[3]) * silu(s2f(zv[3])) * rs * w0.w);
            av[4] = f2b(s2f(yv[4]) * silu(s2f(zv[4])) * rs * w1.x);
            av[5] = f2b(s2f(yv[5]) * silu(s2f(zv[5])) * rs * w1.y);
            av[6] = f2b(s2f(yv[6]) * silu(s2f(zv[6])) * rs * w1.z);
            av[7] = f2b(s2f(yv[7]) * silu(s2f(zv[7])) * rs * w1.w);
            *reinterpret_cast<short8*>(&As[ar * 72 + ak]) = av;
        }
        #pragma unroll
        for (int i = 0; i < 4; i++) {
            int idx = tid + i * 256;
            int n = idx >> 3, kk = (idx & 7) * 8;
            *reinterpret_cast<short8*>(&Bt[n * 72 + kk]) =
                *reinterpret_cast<const short8*>(&wt[n * 256 + k0 + kk]);
        }
        __syncthreads();
        short8 a0 = *reinterpret_cast<const short8*>(&As[(mrow + m) * 72 + kq]);
        short8 a1 = *reinterpret_cast<const short8*>(&As[(mrow + m) * 72 + kq + 32]);
        #pragma unroll
        for (int nt = 0; nt < 4; nt++) {
            int bo = (ngrp * 64 + nt * 16 + m) * 72 + kq;
            short8 b0 = *reinterpret_cast<const short8*>(&Bt[bo]);
            short8 b1 = *reinterpret_cast<const short8*>(&Bt[bo + 32]);
            acc[nt] = __builtin_amdgcn_mfma_f32_16x16x32_bf16(a0, b0, acc[nt], 0, 0, 0);
            acc[nt] = __builtin_amdgcn_mfma_f32_16x16x32_bf16(a1, b1, acc[nt], 0, 0, 0);
        }
    }
    // epilogue: residual in registers, LN stats via shuffle + tiny LDS exchange
    float val[4][4];
    float s1r[4] = {0.f,0.f,0.f,0.f}, s2r[4] = {0.f,0.f,0.f,0.f};
    #pragma unroll
    for (int nt = 0; nt < 4; nt++) {
        int col = ngrp * 64 + nt * 16 + m;
        #pragma unroll
        for (int r = 0; r < 4; r++) {
            int row = row0 + mrow + quad * 4 + r;
            float v = h[(size_t)row * DM + col] + acc[nt][r];
            val[nt][r] = v;
            s1r[r] += v; s2r[r] += v * v;
        }
    }
    #pragma unroll
    for (int o = 1; o < 16; o <<= 1) {
        #pragma unroll
        for (int r = 0; r < 4; r++) {
            s1r[r] += __shfl_xor(s1r[r], o);
            s2r[r] += __shfl_xor(s2r[r], o);
        }
    }
    if (m == 0) {
        #pragma unroll
        for (int r = 0; r < 4; r++) {
            ps1[mrow + quad * 4 + r][ngrp] = s1r[r];
            ps2[mrow + quad * 4 + r][ngrp] = s2r[r];
        }
    }
    __syncthreads();
    #pragma unroll
    for (int r = 0; r < 4; r++) {
        int rl = mrow + quad * 4 + r;
        int row = row0 + rl;
        float s1 = ps1[rl][0] + ps1[rl][1];
        float s2 = ps2[rl][0] + ps2[rl][1];
        float mu = s1 * (1.f / 128.f);
        float rs = rsqrtf(s2 * (1.f / 128.f) - mu * mu + 1e-5f);
        #pragma unroll
        for (int nt = 0; nt < 4; nt++) {
            int col = ngrp * 64 + nt * 16 + m;
            float v = val[nt][r];
            h[(size_t)row * DM + col] = v;
            if (write_hn)
                hnb[(size_t)row * DM + col] = f2b((v - mu) * rs * lnw2[col] + lnb2[col]);
        }
    }
}

// ---------------- fc2a + fc2b fused (M=32, 256thr) ----------------
__global__ __launch_bounds__(256) void fc2ab_mfma(const float* __restrict__ h,
                                                  const short* __restrict__ wb,
                                                  const float* __restrict__ b1,
                                                  const float* __restrict__ W2,
                                                  const float* __restrict__ b2,
                                                  float* __restrict__ out) {
    __shared__ short As[32 * 72];
    __shared__ short Bt[128 * 72];
    __shared__ float h2s[32][132];
    __shared__ float w2s[768];
    int tid = threadIdx.x;
    int lane = tid & 63;
    int m = lane & 15;
    int quad = lane >> 4;
    int kq = quad * 8;
    int w = tid >> 6;
    int mrow = (w & 1) * 16;
    int ngrp = w >> 1;
    int ar = tid >> 3;
    int ak = (tid & 7) * 8;
    int row0 = blockIdx.x * 32;
    const short* wt = wb + WB_FC2;
    for (int i = tid; i < 768; i += 256) w2s[i] = W2[i];
    float4v acc[4];
    acc[0] = (float4v)0.f; acc[1] = (float4v)0.f; acc[2] = (float4v)0.f; acc[3] = (float4v)0.f;
    for (int kt = 0; kt < 2; kt++) {
        int k0 = kt * 64;
        if (kt) __syncthreads();
        {
            const float* src = h + (size_t)(row0 + ar) * DM + k0 + ak;
            float4 v0 = *(const float4*)src;
            float4 v1 = *(const float4*)(src + 4);
            *reinterpret_cast<short8*>(&As[ar * 72 + ak]) = pack8f(v0, v1);
        }
        #pragma unroll
        for (int i = 0; i < 4; i++) {
            int idx = tid + i * 256;
            int n = idx >> 3, kk = (idx & 7) * 8;
            *reinterpret_cast<short8*>(&Bt[n * 72 + kk]) =
                *reinterpret_cast<const short8*>(&wt[n * 128 + k0 + kk]);
        }
        __syncthreads();
        short8 a0 = *reinterpret_cast<const short8*>(&As[(mrow + m) * 72 + kq]);
        short8 a1 = *reinterpret_cast<const short8*>(&As[(mrow + m) * 72 + kq + 32]);
        #pragma unroll
        for (int nt = 0; nt < 4; nt++) {
            int bo = (ngrp * 64 + nt * 16 + m) * 72 + kq;
            short8 b0 = *reinterpret_cast<const short8*>(&Bt[bo]);
            short8 b1 = *reinterpret_cast<const short8*>(&Bt[bo + 32]);
            acc[nt] = __builtin_amdgcn_mfma_f32_16x16x32_bf16(a0, b0, acc[nt], 0, 0, 0);
            acc[nt] = __builtin_amdgcn_mfma_f32_16x16x32_bf16(a1, b1, acc[nt], 0, 0, 0);
        }
    }
    __syncthreads();
    #pragma unroll
    for (int nt = 0; nt < 4; nt++) {
        int col = ngrp * 64 + nt * 16 + m;
        float bv = b1[col];
        #pragma unroll
        for (int r = 0; r < 4; r++) {
            int rr = mrow + quad * 4 + r;
            float o = acc[nt][r] + bv;
            h2s[rr][col] = (o > 0.f) ? o : 0.1f * o;
        }
    }
    __syncthreads();
    if (tid < 192) {
        int r = tid / 6, cc = tid % 6;
        float acc2 = b2[cc];
        #pragma unroll 16
        for (int k = 0; k < 128; k++) acc2 += h2s[r][k] * w2s[k * 6 + cc];
        out[(size_t)(row0 + r) * 6 + cc] = acc2;
    }
}

extern "C" void kernel_launch(void* const* d_in, const int* in_sizes, int n_in,
                              void* d_out, int out_size, void* d_ws, size_t ws_size,
                              hipStream_t stream) {
    const float* x       = (const float*)d_in[0];
    const float* fc1_W   = (const float*)d_in[1];
    const float* fc1_b   = (const float*)d_in[2];
    const float* ln_w    = (const float*)d_in[3];
    const float* ln_b    = (const float*)d_in[4];
    const float* in_W    = (const float*)d_in[5];
    const float* conv_w  = (const float*)d_in[6];
    const float* conv_b  = (const float*)d_in[7];
    const float* dt_bias = (const float*)d_in[8];
    const float* A_log   = (const float*)d_in[9];
    const float* Dp      = (const float*)d_in[10];
    const float* rms_w   = (const float*)d_in[11];
    const float* out_W   = (const float*)d_in[12];
    const float* fc2_W1  = (const float*)d_in[13];
    const float* fc2_b1  = (const float*)d_in[14];
    const float* fc2_W2  = (const float*)d_in[15];
    const float* fc2_b2  = (const float*)d_in[16];
    float* out = (float*)d_out;

    float* ws = (float*)d_ws;
    float* h     = ws;                            // NROWS*DM f32
    float* dtb   = h     + (size_t)NROWS * DM;    // NROWS*NH f32
    float* decay = dtb   + (size_t)NROWS * NH;    // 1024 f32
    short* sbase = (short*)(decay + 1024);
    short* hnb   = sbase;                          // NROWS*DM sh
    short* zb    = hnb   + (size_t)NROWS * DM;     // NROWS*DI sh
    short* xbc   = zb    + (size_t)NROWS * DI;     // NROWS*CDIM sh
    short* xcb   = xbc   + (size_t)NROWS * CDIM;   // NROWS*CDIM sh
    short* ybb   = xcb   + (size_t)NROWS * CDIM;   // NROWS*DI sh
    short* Slocb = ybb   + (size_t)NROWS * DI;     // 1024*4096 sh
    short* hstrb = Slocb + (size_t)BATCH*NH*NCHUNK*HD*DST;
    short* wb    = hstrb + (size_t)BATCH*NH*NCHUNK*HD*DST;

    prep_weights<<<1348, 256, 0, stream>>>(fc1_W, in_W, out_W, fc2_W1, wb);
    fc1_mfma<<<NROWS / 32, 256, 0, stream>>>(x, wb + WB_FC1, fc1_b, ln_w, ln_b, h, hnb);

    for (int layer = 0; layer < 2; layer++) {
        inproj_mfma<<<dim3(NROWS / 64, 6), 512, 0, stream>>>(hnb, wb, zb, xbc, dtb,
                                                             dt_bias, layer);
        conv_kernel<<<NROWS / 4, CDIM, 0, stream>>>(xbc, conv_w, conv_b, xcb, layer);
        chunk_state_mfma<<<BATCH*NH*NCHUNK, 256, 0, stream>>>(xcb, dtb, A_log, Slocb, decay, layer);
        chunk_scan_kernel<<<BATCH*NH, 256, 0, stream>>>(Slocb, decay, hstrb);
        chunk_out_mfma<<<BATCH*NH*NCHUNK, 256, 0, stream>>>(xcb, dtb, A_log, Dp, hstrb, ybb, layer);
        outproj_gate_mfma<<<NROWS / 32, 256, 0, stream>>>(ybb, zb, rms_w, wb,
                                                          ln_w + DM, ln_b + DM, h, hnb,
                                                          layer, layer == 0 ? 1 : 0);
    }

    fc2ab_mfma<<<NROWS / 32, 256, 0, stream>>>(h, wb, fc2_b1, fc2_W2, fc2_b2, out);
}

// Round 13
// 261.439 us; speedup vs baseline: 1.0545x; 1.0545x over previous
//
#include <hip/hip_runtime.h>
#include <hip/hip_bf16.h>

// Dims
#define BATCH 16
#define SEQ 1024
#define NROWS (BATCH*SEQ)          // 16384 tokens
#define IN_DIM 768
#define DM 128
#define DIP 644
#define DI 256
#define CDIM 384
#define DST 64
#define NH 4
#define HD 64
#define CHUNK 64
#define NCHUNK (SEQ/CHUNK)         // 16

// bf16 weight area offsets (in shorts)
#define WB_FC1   0          // [128][768]
#define WB_IN    98304      // [2][644][128]
#define WB_OUT   263168     // [2][128][256]
#define WB_FC2   328704     // [128][128]
#define WB_TOTAL 345088

typedef __attribute__((ext_vector_type(8))) short short8;
typedef __attribute__((ext_vector_type(4))) float float4v;

// f32 -> bf16 (RNE) as raw short
__device__ __forceinline__ short f2b(float f) {
    unsigned u = __builtin_bit_cast(unsigned, f);
    u += 0x7fffu + ((u >> 16) & 1u);
    return (short)(u >> 16);
}
__device__ __forceinline__ float s2f(short s) {
    unsigned u = ((unsigned)(unsigned short)s) << 16;
    return __builtin_bit_cast(float, u);
}
__device__ __forceinline__ short8 pack8f(float4 a, float4 b) {
    short8 r;
    r[0] = f2b(a.x); r[1] = f2b(a.y); r[2] = f2b(a.z); r[3] = f2b(a.w);
    r[4] = f2b(b.x); r[5] = f2b(b.y); r[6] = f2b(b.z); r[7] = f2b(b.w);
    return r;
}
__device__ __forceinline__ float silu(float a) { return a / (1.f + expf(-a)); }

// ---------------- weight prep: convert + transpose to bf16 ----------------
__global__ void prep_weights(const float* __restrict__ fc1_W, const float* __restrict__ in_W,
                             const float* __restrict__ out_W, const float* __restrict__ fc2_W1,
                             short* __restrict__ wb) {
    int idx = blockIdx.x * 256 + threadIdx.x;
    if (idx < 98304) {                       // fc1_Wt[n][k] <- fc1_W[k][n]
        int n = idx / 768, k = idx % 768;
        wb[WB_FC1 + idx] = f2b(fc1_W[k * 128 + n]);
        return;
    }
    idx -= 98304;
    if (idx < 2 * 82432) {                   // in_Wt[l][n][k] <- in_W[l][k][n]
        int l = idx / 82432, r = idx % 82432;
        int n = r / 128, k = r % 128;
        wb[WB_IN + idx] = f2b(in_W[(size_t)l * 82432 + k * 644 + n]);
        return;
    }
    idx -= 164864;
    if (idx < 2 * 32768) {                   // out_Wt[l][n][k] <- out_W[l][k][n]
        int l = idx / 32768, r = idx % 32768;
        int n = r / 256, k = r % 256;
        wb[WB_OUT + idx] = f2b(out_W[(size_t)l * 32768 + k * 128 + n]);
        return;
    }
    idx -= 65536;
    if (idx < 16384) {                       // fc2_W1t[n][k] <- fc2_W1[k][n]
        int n = idx / 128, k = idx % 128;
        wb[WB_FC2 + idx] = f2b(fc2_W1[k * 128 + n]);
    }
}

// ============================================================
// MFMA GEMM tile pattern (block 512 = 8 waves, M=64 x N=128)
// ============================================================
#define GEMM_PROLOGUE() \
    int tid = threadIdx.x; \
    int lane = tid & 63; \
    int m = lane & 15; \
    int kq = (lane >> 4) * 8; \
    int w = tid >> 6; \
    int mrow = (w & 3) * 16; \
    int ngrp = w >> 2; \
    int a_off = (mrow + m) * 72 + kq; \
    int b_off = (ngrp * 64 + m) * 72 + kq; \
    int ar = tid >> 3; \
    int ak = (tid & 7) * 8; \
    (void)ar; (void)ak; \
    float4v acc[4]; \
    acc[0] = (float4v)0.f; acc[1] = (float4v)0.f; acc[2] = (float4v)0.f; acc[3] = (float4v)0.f;

#define GEMM_COMPUTE_TILE() \
    { \
        short8 a0 = *reinterpret_cast<const short8*>(&As[a_off]); \
        short8 a1 = *reinterpret_cast<const short8*>(&As[a_off + 32]); \
        _Pragma("unroll") \
        for (int nt = 0; nt < 4; nt++) { \
            short8 b0 = *reinterpret_cast<const short8*>(&Bt[b_off + nt * 16 * 72]); \
            short8 b1 = *reinterpret_cast<const short8*>(&Bt[b_off + nt * 16 * 72 + 32]); \
            acc[nt] = __builtin_amdgcn_mfma_f32_16x16x32_bf16(a0, b0, acc[nt], 0, 0, 0); \
            acc[nt] = __builtin_amdgcn_mfma_f32_16x16x32_bf16(a1, b1, acc[nt], 0, 0, 0); \
        } \
    }

#define GEMM_STAGE_B(wtptr, LDB, k0) \
    _Pragma("unroll") \
    for (int i = 0; i < 2; i++) { \
        int idx = tid + i * 512; \
        int n = idx >> 3, kk = (idx & 7) * 8; \
        *reinterpret_cast<short8*>(&Bt[n * 72 + kk]) = \
            *reinterpret_cast<const short8*>(&wtptr[n * (LDB) + (k0) + kk]); \
    }

// ---------------- fc1 (MFMA, M=32, 512thr, 512 blocks) + PE + register-LN ----------------
__global__ __launch_bounds__(512) void fc1_mfma(const float* __restrict__ x,
                                                const short* __restrict__ wt,
                                                const float* __restrict__ bias,
                                                const float* __restrict__ lnw0,
                                                const float* __restrict__ lnb0,
                                                float* __restrict__ h,
                                                short* __restrict__ hnb) {
    __shared__ short As[32 * 72];
    __shared__ short Bt[128 * 72];
    __shared__ float ps1[32][4], ps2[32][4];
    int tid = threadIdx.x;
    int lane = tid & 63;
    int m = lane & 15;
    int quad = lane >> 4;
    int kq = quad * 8;
    int w = tid >> 6;              // 0..7
    int mrow = (w & 1) * 16;
    int ngrp = w >> 1;             // 0..3 -> cols ngrp*32 .. +31
    int ar = tid >> 4;             // 0..31
    int ac = (tid & 15) * 4;       // 0..60
    int row0 = blockIdx.x * 32;
    float4v acc[2];
    acc[0] = (float4v)0.f; acc[1] = (float4v)0.f;
    for (int kt = 0; kt < 12; kt++) {
        int k0 = kt * 64;
        if (kt) __syncthreads();
        {
            const float* src = x + (size_t)(row0 + ar) * IN_DIM + k0 + ac;
            float4 v = *(const float4*)src;
            short4 pv;
            pv.x = f2b(v.x); pv.y = f2b(v.y); pv.z = f2b(v.z); pv.w = f2b(v.w);
            *reinterpret_cast<short4*>(&As[ar * 72 + ac]) = pv;
        }
        GEMM_STAGE_B(wt, 768, k0);
        __syncthreads();
        short8 a0 = *reinterpret_cast<const short8*>(&As[(mrow + m) * 72 + kq]);
        short8 a1 = *reinterpret_cast<const short8*>(&As[(mrow + m) * 72 + kq + 32]);
        #pragma unroll
        for (int nt = 0; nt < 2; nt++) {
            int bo = (ngrp * 32 + nt * 16 + m) * 72 + kq;
            short8 b0 = *reinterpret_cast<const short8*>(&Bt[bo]);
            short8 b1 = *reinterpret_cast<const short8*>(&Bt[bo + 32]);
            acc[nt] = __builtin_amdgcn_mfma_f32_16x16x32_bf16(a0, b0, acc[nt], 0, 0, 0);
            acc[nt] = __builtin_amdgcn_mfma_f32_16x16x32_bf16(a1, b1, acc[nt], 0, 0, 0);
        }
    }
    // epilogue: bias + PE in registers, LN stats via shuffle + tiny LDS exchange
    float val[2][4];
    float s1r[4] = {0.f,0.f,0.f,0.f}, s2r[4] = {0.f,0.f,0.f,0.f};
    #pragma unroll
    for (int nt = 0; nt < 2; nt++) {
        int col = ngrp * 32 + nt * 16 + m;
        float bv = bias[col];
        float div = expf(-(float)(col & ~1) * 0.071955784f);
        #pragma unroll
        for (int r = 0; r < 4; r++) {
            int row = row0 + mrow + quad * 4 + r;
            int t = row & (SEQ - 1);
            float arg = (float)t * div;
            float pe = (col & 1) ? cosf(arg) : sinf(arg);
            float v = acc[nt][r] + bv + pe;
            val[nt][r] = v;
            s1r[r] += v; s2r[r] += v * v;
        }
    }
    #pragma unroll
    for (int o = 1; o < 16; o <<= 1) {
        #pragma unroll
        for (int r = 0; r < 4; r++) {
            s1r[r] += __shfl_xor(s1r[r], o);
            s2r[r] += __shfl_xor(s2r[r], o);
        }
    }
    if (m == 0) {
        #pragma unroll
        for (int r = 0; r < 4; r++) {
            ps1[mrow + quad * 4 + r][ngrp] = s1r[r];
            ps2[mrow + quad * 4 + r][ngrp] = s2r[r];
        }
    }
    __syncthreads();
    #pragma unroll
    for (int r = 0; r < 4; r++) {
        int rl = mrow + quad * 4 + r;
        float s1 = ps1[rl][0] + ps1[rl][1] + ps1[rl][2] + ps1[rl][3];
        float s2 = ps2[rl][0] + ps2[rl][1] + ps2[rl][2] + ps2[rl][3];
        float mu = s1 * (1.f / 128.f);
        float rs = rsqrtf(s2 * (1.f / 128.f) - mu * mu + 1e-5f);
        int row = row0 + rl;
        #pragma unroll
        for (int nt = 0; nt < 2; nt++) {
            int col = ngrp * 32 + nt * 16 + m;
            float v = val[nt][r];
            h[(size_t)row * DM + col] = v;
            hnb[(size_t)row * DM + col] = f2b((v - mu) * rs * lnw0[col] + lnb0[col]);
        }
    }
}

// ---------------- in_proj: z->bf16 zb, xBC->bf16, dt->softplus->dtb ----------------
__global__ __launch_bounds__(512) void inproj_mfma(const short* __restrict__ hnb,
                                                   const short* __restrict__ wb,
                                                   short* __restrict__ zb,
                                                   short* __restrict__ xbc,
                                                   float* __restrict__ dtb,
                                                   const float* __restrict__ dt_bias, int layer) {
    __shared__ short As[64 * 72];
    __shared__ short Bt[128 * 72];
    GEMM_PROLOGUE();
    int row0 = blockIdx.x * 64;
    int ncol0 = blockIdx.y * 128;
    const short* wt = wb + WB_IN + (size_t)layer * 82432;
    for (int kt = 0; kt < 2; kt++) {
        int k0 = kt * 64;
        if (kt) __syncthreads();
        *reinterpret_cast<short8*>(&As[ar * 72 + ak]) =
            *reinterpret_cast<const short8*>(&hnb[(size_t)(row0 + ar) * DM + k0 + ak]);
        #pragma unroll
        for (int i = 0; i < 2; i++) {
            int idx = tid + i * 512;
            int n = idx >> 3, kk = (idx & 7) * 8;
            int col = ncol0 + n;
            short8 bv = (short8)0;
            if (col < DIP) bv = *reinterpret_cast<const short8*>(&wt[col * 128 + k0 + kk]);
            *reinterpret_cast<short8*>(&Bt[n * 72 + kk]) = bv;
        }
        __syncthreads();
        GEMM_COMPUTE_TILE();
    }
    #pragma unroll
    for (int nt = 0; nt < 4; nt++) {
        int col = ncol0 + ngrp * 64 + nt * 16 + m;
        if (col < DI) {
            #pragma unroll
            for (int r = 0; r < 4; r++) {
                int row = row0 + mrow + (lane >> 4) * 4 + r;
                zb[(size_t)row * DI + col] = f2b(acc[nt][r]);
            }
        } else if (col < DI + CDIM) {
            #pragma unroll
            for (int r = 0; r < 4; r++) {
                int row = row0 + mrow + (lane >> 4) * 4 + r;
                xbc[(size_t)row * CDIM + (col - DI)] = f2b(acc[nt][r]);
            }
        } else if (col < DIP) {
            int hh = col - DI - CDIM;
            float db = dt_bias[layer * NH + hh];
            #pragma unroll
            for (int r = 0; r < 4; r++) {
                int row = row0 + mrow + (lane >> 4) * 4 + r;
                float raw = acc[nt][r] + db;
                float dt = (raw > 20.f) ? raw : log1pf(expf(raw));
                dtb[(size_t)row * NH + hh] = dt;
            }
        }
    }
}

// ---------------- causal conv(4) + SiLU, 4 tokens/block (bf16 in/out) ----------------
__global__ void conv_kernel(const short* __restrict__ xbc,
                            const float* __restrict__ convw, const float* __restrict__ convb,
                            short* __restrict__ xcb, int layer) {
    int c = threadIdx.x;            // 384
    int row0 = blockIdx.x * 4;
    int l0 = row0 & (SEQ - 1);
    const float* cw = convw + (size_t)layer * 4 * CDIM;
    float w0 = cw[c], w1 = cw[CDIM + c], w2 = cw[2 * CDIM + c], w3 = cw[3 * CDIM + c];
    float bb = convb[layer * CDIM + c];
    float v[7];
    #pragma unroll
    for (int i = 0; i < 7; i++) {
        int rr = row0 + i - 3;
        v[i] = (l0 + i - 3 >= 0) ? s2f(xbc[(size_t)rr * CDIM + c]) : 0.f;
    }
    #pragma unroll
    for (int j = 0; j < 4; j++) {
        float acc = bb + w0 * v[j] + w1 * v[j + 1] + w2 * v[j + 2] + w3 * v[j + 3];
        xcb[(size_t)(row0 + j) * CDIM + c] = f2b(silu(acc));
    }
}

// ---------------- chunk A (MFMA): S[p][n] -> bf16 ----------------
__global__ __launch_bounds__(256) void chunk_state_mfma(const short* __restrict__ xcb,
                                                        const float* __restrict__ dtb,
                                                        const float* __restrict__ A_log,
                                                        short* __restrict__ Slocb,
                                                        float* __restrict__ decay, int layer) {
    __shared__ short XTw[64 * 72];   // [p][t]
    __shared__ short BT[64 * 72];    // [n][t]
    __shared__ float wst[64];
    int bid = blockIdx.x;
    int c  = bid & (NCHUNK - 1);
    int hh = (bid >> 4) & (NH - 1);
    int b  = bid >> 6;
    int tid = threadIdx.x;
    int row0 = b * SEQ + c * CHUNK;
    float A = -expf(A_log[layer * NH + hh]);

    if (tid < CHUNK) {
        float dtv = dtb[(size_t)(row0 + tid) * NH + hh];
        float l = dtv * A;
        #pragma unroll
        for (int o = 1; o < 64; o <<= 1) { float v = __shfl_up(l, o); if (tid >= o) l += v; }
        float Ltot = __shfl(l, 63);
        wst[tid] = expf(Ltot - l) * dtv;
        if (tid == 63) decay[bid] = expf(Ltot);
    }
    __syncthreads();
    {
        int p = tid & 63;
        int tb0 = tid >> 6;
        #pragma unroll
        for (int i = 0; i < 2; i++) {
            int t0 = (tb0 + i * 4) * 8;
            short8 xv, bv;
            #pragma unroll
            for (int j = 0; j < 8; j++) {
                int t = t0 + j;
                const short* xr = xcb + (size_t)(row0 + t) * CDIM;
                xv[j] = f2b(s2f(xr[hh * HD + p]) * wst[t]);
                bv[j] = xr[DI + p];
            }
            *reinterpret_cast<short8*>(&XTw[p * 72 + t0]) = xv;
            *reinterpret_cast<short8*>(&BT[p * 72 + t0]) = bv;
        }
    }
    __syncthreads();

    int lane = tid & 63;
    int m = lane & 15;
    int kq = (lane >> 4) * 8;
    int w = tid >> 6;
    int a_off = (w * 16 + m) * 72 + kq;
    float4v acc[4];
    acc[0] = (float4v)0.f; acc[1] = (float4v)0.f; acc[2] = (float4v)0.f; acc[3] = (float4v)0.f;
    short8 a0 = *reinterpret_cast<const short8*>(&XTw[a_off]);
    short8 a1 = *reinterpret_cast<const short8*>(&XTw[a_off + 32]);
    #pragma unroll
    for (int nt = 0; nt < 4; nt++) {
        int bo = (nt * 16 + m) * 72 + kq;
        short8 b0 = *reinterpret_cast<const short8*>(&BT[bo]);
        short8 b1 = *reinterpret_cast<const short8*>(&BT[bo + 32]);
        acc[nt] = __builtin_amdgcn_mfma_f32_16x16x32_bf16(a0, b0, acc[nt], 0, 0, 0);
        acc[nt] = __builtin_amdgcn_mfma_f32_16x16x32_bf16(a1, b1, acc[nt], 0, 0, 0);
    }
    short* Sp = Slocb + (size_t)bid * (HD * DST);
    int tq = (lane >> 4) * 4;
    #pragma unroll
    for (int nt = 0; nt < 4; nt++) {
        #pragma unroll
        for (int r = 0; r < 4; r++) {
            int p = w * 16 + tq + r;
            int n = nt * 16 + m;
            Sp[p * DST + n] = f2b(acc[nt][r]);   // [p][n] bf16
        }
    }
}

// ---------------- chunk B: inter-chunk recurrence (bf16 io, f32 accum) ----------------
__global__ void chunk_scan_kernel(const short* __restrict__ Slocb, const float* __restrict__ decay,
                                  short* __restrict__ hstrb) {
    int bh = blockIdx.x;
    int tid = threadIdx.x;
    float hreg[16];
    #pragma unroll
    for (int k = 0; k < 16; k++) hreg[k] = 0.f;
    for (int c = 0; c < NCHUNK; c++) {
        size_t base = ((size_t)bh * NCHUNK + c) * (HD * DST) + tid * 16;
        float d = decay[bh * NCHUNK + c];
        short8 s0 = *reinterpret_cast<const short8*>(&Slocb[base]);
        short8 s1 = *reinterpret_cast<const short8*>(&Slocb[base + 8]);
        short8 h0, h1;
        #pragma unroll
        for (int k = 0; k < 8; k++) { h0[k] = f2b(hreg[k]); h1[k] = f2b(hreg[8 + k]); }
        *reinterpret_cast<short8*>(&hstrb[base]) = h0;
        *reinterpret_cast<short8*>(&hstrb[base + 8]) = h1;
        #pragma unroll
        for (int k = 0; k < 8; k++) {
            hreg[k]     = d * hreg[k]     + s2f(s0[k]);
            hreg[8 + k] = d * hreg[8 + k] + s2f(s1[k]);
        }
    }
}

// ---------------- chunk C (MFMA): outputs -> y bf16 ----------------
__global__ __launch_bounds__(256) void chunk_out_mfma(const short* __restrict__ xcb,
                                                      const float* __restrict__ dtb,
                                                      const float* __restrict__ A_log,
                                                      const float* __restrict__ Dpw,
                                                      const short* __restrict__ hstrb,
                                                      short* __restrict__ ybb, int layer) {
    __shared__ short Cb[64 * 72];    // [t][n]
    __shared__ short Bb[64 * 72];    // [s][n], later M[t][s]
    __shared__ short XT[64 * 72];    // [p][t]
    __shared__ short HT[64 * 72];    // [p][n]
    __shared__ float Ls[64], dts[64];
    int bid = blockIdx.x;
    int c  = bid & (NCHUNK - 1);
    int hh = (bid >> 4) & (NH - 1);
    int b  = bid >> 6;
    int tid = threadIdx.x;
    int row0 = b * SEQ + c * CHUNK;
    float A = -expf(A_log[layer * NH + hh]);
    float Dph = Dpw[layer * NH + hh];

    if (tid < CHUNK) {
        float dtv = dtb[(size_t)(row0 + tid) * NH + hh];
        float l = dtv * A;
        #pragma unroll
        for (int o = 1; o < 64; o <<= 1) { float v = __shfl_up(l, o); if (tid >= o) l += v; }
        Ls[tid] = l;
        dts[tid] = dtv;
    }
    {
        int p = tid & 63;
        int tb0 = tid >> 6;
        #pragma unroll
        for (int i = 0; i < 2; i++) {
            int t0 = (tb0 + i * 4) * 8;
            short8 xv;
            #pragma unroll
            for (int j = 0; j < 8; j++)
                xv[j] = xcb[(size_t)(row0 + t0 + j) * CDIM + hh * HD + p];
            *reinterpret_cast<short8*>(&XT[p * 72 + t0]) = xv;
        }
    }
    #pragma unroll
    for (int i = 0; i < 2; i++) {   // Bb, Cb: direct bf16 copies
        int idx = tid + i * 256;
        int t = idx >> 3, cb = (idx & 7) * 8;
        const short* xr = xcb + (size_t)(row0 + t) * CDIM;
        *reinterpret_cast<short8*>(&Bb[t * 72 + cb]) =
            *reinterpret_cast<const short8*>(&xr[DI + cb]);
        *reinterpret_cast<short8*>(&Cb[t * 72 + cb]) =
            *reinterpret_cast<const short8*>(&xr[DI + DST + cb]);
    }
    {
        const short* hs = hstrb + (size_t)bid * (HD * DST);   // [p][n]
        #pragma unroll
        for (int i = 0; i < 2; i++) {
            int idx = tid + i * 256;
            int pp = idx >> 3, nb = (idx & 7) * 8;
            *reinterpret_cast<short8*>(&HT[pp * 72 + nb]) =
                *reinterpret_cast<const short8*>(&hs[pp * 64 + nb]);
        }
    }
    __syncthreads();

    int lane = tid & 63;
    int m = lane & 15;
    int kq = (lane >> 4) * 8;
    int w = tid >> 6;
    int tq = (lane >> 4) * 4;
    int a_off = (w * 16 + m) * 72 + kq;

    short8 ca0 = *reinterpret_cast<const short8*>(&Cb[a_off]);
    short8 ca1 = *reinterpret_cast<const short8*>(&Cb[a_off + 32]);

    float4v g[4], ir[4];
    #pragma unroll
    for (int i = 0; i < 4; i++) { g[i] = (float4v)0.f; ir[i] = (float4v)0.f; }
    #pragma unroll
    for (int st = 0; st < 4; st++) {
        int bo = (st * 16 + m) * 72 + kq;
        short8 b0 = *reinterpret_cast<const short8*>(&Bb[bo]);
        short8 b1 = *reinterpret_cast<const short8*>(&Bb[bo + 32]);
        g[st] = __builtin_amdgcn_mfma_f32_16x16x32_bf16(ca0, b0, g[st], 0, 0, 0);
        g[st] = __builtin_amdgcn_mfma_f32_16x16x32_bf16(ca1, b1, g[st], 0, 0, 0);
        short8 h0 = *reinterpret_cast<const short8*>(&HT[bo]);
        short8 h1 = *reinterpret_cast<const short8*>(&HT[bo + 32]);
        ir[st] = __builtin_amdgcn_mfma_f32_16x16x32_bf16(ca0, h0, ir[st], 0, 0, 0);
        ir[st] = __builtin_amdgcn_mfma_f32_16x16x32_bf16(ca1, h1, ir[st], 0, 0, 0);
    }
    __syncthreads();
    #pragma unroll
    for (int st = 0; st < 4; st++) {
        #pragma unroll
        for (int r = 0; r < 4; r++) {
            int t = w * 16 + tq + r;
            int s = st * 16 + m;
            float mv = 0.f;
            if (s <= t) mv = g[st][r] * expf(Ls[t] - Ls[s]) * dts[s];
            Bb[t * 72 + s] = f2b(mv);
        }
    }
    __syncthreads();
    float4v yi[4];
    #pragma unroll
    for (int i = 0; i < 4; i++) yi[i] = (float4v)0.f;
    short8 ma0 = *reinterpret_cast<const short8*>(&Bb[a_off]);
    short8 ma1 = *reinterpret_cast<const short8*>(&Bb[a_off + 32]);
    #pragma unroll
    for (int pt = 0; pt < 4; pt++) {
        int bo = (pt * 16 + m) * 72 + kq;
        short8 x0 = *reinterpret_cast<const short8*>(&XT[bo]);
        short8 x1 = *reinterpret_cast<const short8*>(&XT[bo + 32]);
        yi[pt] = __builtin_amdgcn_mfma_f32_16x16x32_bf16(ma0, x0, yi[pt], 0, 0, 0);
        yi[pt] = __builtin_amdgcn_mfma_f32_16x16x32_bf16(ma1, x1, yi[pt], 0, 0, 0);
    }
    #pragma unroll
    for (int r = 0; r < 4; r++) {
        int t = w * 16 + tq + r;
        float et = expf(Ls[t]);
        short* yr = ybb + (size_t)(row0 + t) * DI + hh * HD;
        #pragma unroll
        for (int pt = 0; pt < 4; pt++) {
            int p = pt * 16 + m;
            float xv = s2f(XT[p * 72 + t]);
            yr[p] = f2b(yi[pt][r] + et * ir[pt][r] + Dph * xv);
        }
    }
}

// ---------------- out_proj + gate/RMSNorm + residual + fused next-layer LN ----------------
__global__ __launch_bounds__(512) void outproj_gate_mfma(const short* __restrict__ ybb,
                                                         const short* __restrict__ zb,
                                                         const float* __restrict__ rmsw,
                                                         const short* __restrict__ wb,
                                                         const float* __restrict__ lnw2,
                                                         const float* __restrict__ lnb2,
                                                         float* __restrict__ h,
                                                         short* __restrict__ hnb,
                                                         int layer, int write_hn) {
    __shared__ __align__(16) char smem[64 * 133 * 4];
    short* As = (short*)smem;
    short* Bt = (short*)(smem + 64 * 72 * 2);
    float* hs = (float*)smem;                  // overlaid
    __shared__ float rs_s[64];
    GEMM_PROLOGUE();
    int row0 = blockIdx.x * 64;
    const short* wt = wb + WB_OUT + (size_t)layer * 32768;
    {   // RMS stats on v = y*silu(z): 8 threads/row, 32 cols each
        int r = tid >> 3, j = tid & 7;
        const short8* yr = (const short8*)(ybb + (size_t)(row0 + r) * DI + j * 32);
        const short8* zr = (const short8*)(zb + (size_t)(row0 + r) * DI + j * 32);
        float s2 = 0.f;
        #pragma unroll
        for (int i = 0; i < 4; i++) {
            short8 yv = yr[i];
            short8 zv = zr[i];
            #pragma unroll
            for (int q = 0; q < 8; q++) {
                float v = s2f(yv[q]) * silu(s2f(zv[q]));
                s2 += v * v;
            }
        }
        #pragma unroll
        for (int o = 1; o < 8; o <<= 1) s2 += __shfl_xor(s2, o);
        if (j == 0) rs_s[r] = rsqrtf(s2 * (1.f / 256.f) + 1e-5f);
    }
    __syncthreads();
    for (int kt = 0; kt < 4; kt++) {
        int k0 = kt * 64;
        if (kt) __syncthreads();
        {
            int k = k0 + ak;
            short8 yv = *(const short8*)(ybb + (size_t)(row0 + ar) * DI + k);
            short8 zv = *(const short8*)(zb + (size_t)(row0 + ar) * DI + k);
            float4 w0 = *(const float4*)(rmsw + layer * DI + k);
            float4 w1 = *(const float4*)(rmsw + layer * DI + k + 4);
            float rs = rs_s[ar];
            short8 av;
            av[0] = f2b(s2f(yv[0]) * silu(s2f(zv[0])) * rs * w0.x);
            av[1] = f2b(s2f(yv[1]) * silu(s2f(zv[1])) * rs * w0.y);
            av[2] = f2b(s2f(yv[2]) * silu(s2f(zv[2])) * rs * w0.z);
            av[3] = f2b(s2f(yv[3]) * silu(s2f(zv[3])) * rs * w0.w);
            av[4] = f2b(s2f(yv[4]) * silu(s2f(zv[4])) * rs * w1.x);
            av[5] = f2b(s2f(yv[5]) * silu(s2f(zv[5])) * rs * w1.y);
            av[6] = f2b(s2f(yv[6]) * silu(s2f(zv[6])) * rs * w1.z);
            av[7] = f2b(s2f(yv[7]) * silu(s2f(zv[7])) * rs * w1.w);
            *reinterpret_cast<short8*>(&As[ar * 72 + ak]) = av;
        }
        GEMM_STAGE_B(wt, 256, k0);
        __syncthreads();
        GEMM_COMPUTE_TILE();
    }
    __syncthreads();   // done with As/Bt; reuse as hs
    #pragma unroll
    for (int nt = 0; nt < 4; nt++) {
        int col = ngrp * 64 + nt * 16 + m;
        #pragma unroll
        for (int r = 0; r < 4; r++) {
            int rr = mrow + (lane >> 4) * 4 + r;
            hs[rr * 133 + col] = acc[nt][r];
        }
    }
    __syncthreads();
    {   // residual add + LN + stores
        int r = tid >> 3, j = tid & 7;
        int row = row0 + r;
        float* hdst = h + (size_t)row * DM + j * 16;
        float vals[16]; float s1 = 0.f, s2 = 0.f;
        #pragma unroll
        for (int i = 0; i < 4; i++) {
            float4 ho = *(const float4*)(hdst + i * 4);
            float v0 = ho.x + hs[r * 133 + j * 16 + i * 4];
            float v1 = ho.y + hs[r * 133 + j * 16 + i * 4 + 1];
            float v2 = ho.z + hs[r * 133 + j * 16 + i * 4 + 2];
            float v3 = ho.w + hs[r * 133 + j * 16 + i * 4 + 3];
            vals[i*4] = v0; vals[i*4+1] = v1; vals[i*4+2] = v2; vals[i*4+3] = v3;
            s1 += v0 + v1 + v2 + v3;
            s2 += v0*v0 + v1*v1 + v2*v2 + v3*v3;
        }
        #pragma unroll
        for (int o = 1; o < 8; o <<= 1) { s1 += __shfl_xor(s1, o); s2 += __shfl_xor(s2, o); }
        #pragma unroll
        for (int i = 0; i < 4; i++)
            *(float4*)(hdst + i * 4) = make_float4(vals[i*4], vals[i*4+1], vals[i*4+2], vals[i*4+3]);
        if (write_hn) {
            float mu = s1 * (1.f / 128.f);
            float rs = rsqrtf(s2 * (1.f / 128.f) - mu * mu + 1e-5f);
            const float* lw = lnw2 + j * 16;
            const float* lb = lnb2 + j * 16;
            short8 a0, a1;
            #pragma unroll
            for (int i = 0; i < 8; i++) {
                a0[i] = f2b((vals[i] - mu) * rs * lw[i] + lb[i]);
                a1[i] = f2b((vals[8 + i] - mu) * rs * lw[8 + i] + lb[8 + i]);
            }
            short* hndst = hnb + (size_t)row * DM + j * 16;
            *reinterpret_cast<short8*>(hndst) = a0;
            *reinterpret_cast<short8*>(hndst + 8) = a1;
        }
    }
}

// ---------------- fc2a + fc2b fused ----------------
__global__ __launch_bounds__(512) void fc2ab_mfma(const float* __restrict__ h,
                                                  const short* __restrict__ wb,
                                                  const float* __restrict__ b1,
                                                  const float* __restrict__ W2,
                                                  const float* __restrict__ b2,
                                                  float* __restrict__ out) {
    __shared__ short As[64 * 72];
    __shared__ short Bt[128 * 72];
    __shared__ float h2s[64][132];
    __shared__ float w2s[768];
    GEMM_PROLOGUE();
    int row0 = blockIdx.x * 64;
    const short* wt = wb + WB_FC2;
    for (int i = tid; i < 768; i += 512) w2s[i] = W2[i];
    for (int kt = 0; kt < 2; kt++) {
        int k0 = kt * 64;
        if (kt) __syncthreads();
        {
            const float* src = h + (size_t)(row0 + ar) * DM + k0 + ak;
            float4 v0 = *(const float4*)src;
            float4 v1 = *(const float4*)(src + 4);
            *reinterpret_cast<short8*>(&As[ar * 72 + ak]) = pack8f(v0, v1);
        }
        GEMM_STAGE_B(wt, 128, k0);
        __syncthreads();
        GEMM_COMPUTE_TILE();
    }
    #pragma unroll
    for (int nt = 0; nt < 4; nt++) {
        int col = ngrp * 64 + nt * 16 + m;
        float bv = b1[col];
        #pragma unroll
        for (int r = 0; r < 4; r++) {
            int rr = mrow + (lane >> 4) * 4 + r;
            float o = acc[nt][r] + bv;
            h2s[rr][col] = (o > 0.f) ? o : 0.1f * o;
        }
    }
    __syncthreads();
    if (tid < 384) {
        int r = tid / 6, cc = tid % 6;
        float acc2 = b2[cc];
        #pragma unroll 16
        for (int k = 0; k < 128; k++) acc2 += h2s[r][k] * w2s[k * 6 + cc];
        out[(size_t)(row0 + r) * 6 + cc] = acc2;
    }
}

extern "C" void kernel_launch(void* const* d_in, const int* in_sizes, int n_in,
                              void* d_out, int out_size, void* d_ws, size_t ws_size,
                              hipStream_t stream) {
    const float* x       = (const float*)d_in[0];
    const float* fc1_W   = (const float*)d_in[1];
    const float* fc1_b   = (const float*)d_in[2];
    const float* ln_w    = (const float*)d_in[3];
    const float* ln_b    = (const float*)d_in[4];
    const float* in_W    = (const float*)d_in[5];
    const float* conv_w  = (const float*)d_in[6];
    const float* conv_b  = (const float*)d_in[7];
    const float* dt_bias = (const float*)d_in[8];
    const float* A_log   = (const float*)d_in[9];
    const float* Dp      = (const float*)d_in[10];
    const float* rms_w   = (const float*)d_in[11];
    const float* out_W   = (const float*)d_in[12];
    const float* fc2_W1  = (const float*)d_in[13];
    const float* fc2_b1  = (const float*)d_in[14];
    const float* fc2_W2  = (const float*)d_in[15];
    const float* fc2_b2  = (const float*)d_in[16];
    float* out = (float*)d_out;

    float* ws = (float*)d_ws;
    float* h     = ws;                            // NROWS*DM f32
    float* dtb   = h     + (size_t)NROWS * DM;    // NROWS*NH f32
    float* decay = dtb   + (size_t)NROWS * NH;    // 1024 f32
    short* sbase = (short*)(decay + 1024);
    short* hnb   = sbase;                          // NROWS*DM sh
    short* zb    = hnb   + (size_t)NROWS * DM;     // NROWS*DI sh
    short* xbc   = zb    + (size_t)NROWS * DI;     // NROWS*CDIM sh
    short* xcb   = xbc   + (size_t)NROWS * CDIM;   // NROWS*CDIM sh
    short* ybb   = xcb   + (size_t)NROWS * CDIM;   // NROWS*DI sh
    short* Slocb = ybb   + (size_t)NROWS * DI;     // 1024*4096 sh
    short* hstrb = Slocb + (size_t)BATCH*NH*NCHUNK*HD*DST;
    short* wb    = hstrb + (size_t)BATCH*NH*NCHUNK*HD*DST;

    prep_weights<<<1348, 256, 0, stream>>>(fc1_W, in_W, out_W, fc2_W1, wb);
    fc1_mfma<<<NROWS / 32, 512, 0, stream>>>(x, wb + WB_FC1, fc1_b, ln_w, ln_b, h, hnb);

    for (int layer = 0; layer < 2; layer++) {
        inproj_mfma<<<dim3(NROWS / 64, 6), 512, 0, stream>>>(hnb, wb, zb, xbc, dtb,
                                                             dt_bias, layer);
        conv_kernel<<<NROWS / 4, CDIM, 0, stream>>>(xbc, conv_w, conv_b, xcb, layer);
        chunk_state_mfma<<<BATCH*NH*NCHUNK, 256, 0, stream>>>(xcb, dtb, A_log, Slocb, decay, layer);
        chunk_scan_kernel<<<BATCH*NH, 256, 0, stream>>>(Slocb, decay, hstrb);
        chunk_out_mfma<<<BATCH*NH*NCHUNK, 256, 0, stream>>>(xcb, dtb, A_log, Dp, hstrb, ybb, layer);
        outproj_gate_mfma<<<NROWS / 64, 512, 0, stream>>>(ybb, zb, rms_w, wb,
                                                          ln_w + DM, ln_b + DM, h, hnb,
                                                          layer, layer == 0 ? 1 : 0);
    }

    fc2ab_mfma<<<NROWS / 64, 512, 0, stream>>>(h, wb, fc2_b1, fc2_W2, fc2_b2, out);
}

// Round 14
// 259.975 us; speedup vs baseline: 1.0605x; 1.0056x over previous
//
#include <hip/hip_runtime.h>
#include <hip/hip_bf16.h>

// Dims
#define BATCH 16
#define SEQ 1024
#define NROWS (BATCH*SEQ)          // 16384 tokens
#define IN_DIM 768
#define DM 128
#define DIP 644
#define DI 256
#define CDIM 384
#define DST 64
#define NH 4
#define HD 64
#define CHUNK 64
#define NCHUNK (SEQ/CHUNK)         // 16

// bf16 weight area offsets (in shorts)
#define WB_FC1   0          // [128][768]
#define WB_IN    98304      // [2][644][128]
#define WB_OUT   263168     // [2][128][256]
#define WB_FC2   328704     // [128][128]
#define WB_TOTAL 345088

typedef __attribute__((ext_vector_type(8))) short short8;
typedef __attribute__((ext_vector_type(4))) float float4v;

// f32 -> bf16 (RNE) as raw short
__device__ __forceinline__ short f2b(float f) {
    unsigned u = __builtin_bit_cast(unsigned, f);
    u += 0x7fffu + ((u >> 16) & 1u);
    return (short)(u >> 16);
}
__device__ __forceinline__ float s2f(short s) {
    unsigned u = ((unsigned)(unsigned short)s) << 16;
    return __builtin_bit_cast(float, u);
}
__device__ __forceinline__ short8 pack8f(float4 a, float4 b) {
    short8 r;
    r[0] = f2b(a.x); r[1] = f2b(a.y); r[2] = f2b(a.z); r[3] = f2b(a.w);
    r[4] = f2b(b.x); r[5] = f2b(b.y); r[6] = f2b(b.z); r[7] = f2b(b.w);
    return r;
}
__device__ __forceinline__ float silu(float a) { return a / (1.f + expf(-a)); }

// ---------------- weight prep: convert + transpose to bf16 ----------------
__global__ void prep_weights(const float* __restrict__ fc1_W, const float* __restrict__ in_W,
                             const float* __restrict__ out_W, const float* __restrict__ fc2_W1,
                             short* __restrict__ wb) {
    int idx = blockIdx.x * 256 + threadIdx.x;
    if (idx < 98304) {                       // fc1_Wt[n][k] <- fc1_W[k][n]
        int n = idx / 768, k = idx % 768;
        wb[WB_FC1 + idx] = f2b(fc1_W[k * 128 + n]);
        return;
    }
    idx -= 98304;
    if (idx < 2 * 82432) {                   // in_Wt[l][n][k] <- in_W[l][k][n]
        int l = idx / 82432, r = idx % 82432;
        int n = r / 128, k = r % 128;
        wb[WB_IN + idx] = f2b(in_W[(size_t)l * 82432 + k * 644 + n]);
        return;
    }
    idx -= 164864;
    if (idx < 2 * 32768) {                   // out_Wt[l][n][k] <- out_W[l][k][n]
        int l = idx / 32768, r = idx % 32768;
        int n = r / 256, k = r % 256;
        wb[WB_OUT + idx] = f2b(out_W[(size_t)l * 32768 + k * 128 + n]);
        return;
    }
    idx -= 65536;
    if (idx < 16384) {                       // fc2_W1t[n][k] <- fc2_W1[k][n]
        int n = idx / 128, k = idx % 128;
        wb[WB_FC2 + idx] = f2b(fc2_W1[k * 128 + n]);
    }
}

// ============================================================
// MFMA GEMM tile pattern (block 512 = 8 waves, M=64 x N=128)
// ============================================================
#define GEMM_PROLOGUE() \
    int tid = threadIdx.x; \
    int lane = tid & 63; \
    int m = lane & 15; \
    int kq = (lane >> 4) * 8; \
    int w = tid >> 6; \
    int mrow = (w & 3) * 16; \
    int ngrp = w >> 2; \
    int a_off = (mrow + m) * 72 + kq; \
    int b_off = (ngrp * 64 + m) * 72 + kq; \
    int ar = tid >> 3; \
    int ak = (tid & 7) * 8; \
    (void)ar; (void)ak; \
    float4v acc[4]; \
    acc[0] = (float4v)0.f; acc[1] = (float4v)0.f; acc[2] = (float4v)0.f; acc[3] = (float4v)0.f;

#define GEMM_COMPUTE_TILE() \
    { \
        short8 a0 = *reinterpret_cast<const short8*>(&As[a_off]); \
        short8 a1 = *reinterpret_cast<const short8*>(&As[a_off + 32]); \
        _Pragma("unroll") \
        for (int nt = 0; nt < 4; nt++) { \
            short8 b0 = *reinterpret_cast<const short8*>(&Bt[b_off + nt * 16 * 72]); \
            short8 b1 = *reinterpret_cast<const short8*>(&Bt[b_off + nt * 16 * 72 + 32]); \
            acc[nt] = __builtin_amdgcn_mfma_f32_16x16x32_bf16(a0, b0, acc[nt], 0, 0, 0); \
            acc[nt] = __builtin_amdgcn_mfma_f32_16x16x32_bf16(a1, b1, acc[nt], 0, 0, 0); \
        } \
    }

#define GEMM_STAGE_B(wtptr, LDB, k0) \
    _Pragma("unroll") \
    for (int i = 0; i < 2; i++) { \
        int idx = tid + i * 512; \
        int n = idx >> 3, kk = (idx & 7) * 8; \
        *reinterpret_cast<short8*>(&Bt[n * 72 + kk]) = \
            *reinterpret_cast<const short8*>(&wtptr[n * (LDB) + (k0) + kk]); \
    }

// ---------------- fc1 (MFMA, M=32, 512thr, 512 blocks) + PE + register-LN ----------------
__global__ __launch_bounds__(512) void fc1_mfma(const float* __restrict__ x,
                                                const short* __restrict__ wt,
                                                const float* __restrict__ bias,
                                                const float* __restrict__ lnw0,
                                                const float* __restrict__ lnb0,
                                                float* __restrict__ h,
                                                short* __restrict__ hnb) {
    __shared__ short As[32 * 72];
    __shared__ short Bt[128 * 72];
    __shared__ float ps1[32][4], ps2[32][4];
    int tid = threadIdx.x;
    int lane = tid & 63;
    int m = lane & 15;
    int quad = lane >> 4;
    int kq = quad * 8;
    int w = tid >> 6;              // 0..7
    int mrow = (w & 1) * 16;
    int ngrp = w >> 1;             // 0..3 -> cols ngrp*32 .. +31
    int ar = tid >> 4;             // 0..31
    int ac = (tid & 15) * 4;       // 0..60
    int row0 = blockIdx.x * 32;
    float4v acc[2];
    acc[0] = (float4v)0.f; acc[1] = (float4v)0.f;
    for (int kt = 0; kt < 12; kt++) {
        int k0 = kt * 64;
        if (kt) __syncthreads();
        {
            const float* src = x + (size_t)(row0 + ar) * IN_DIM + k0 + ac;
            float4 v = *(const float4*)src;
            short4 pv;
            pv.x = f2b(v.x); pv.y = f2b(v.y); pv.z = f2b(v.z); pv.w = f2b(v.w);
            *reinterpret_cast<short4*>(&As[ar * 72 + ac]) = pv;
        }
        GEMM_STAGE_B(wt, 768, k0);
        __syncthreads();
        short8 a0 = *reinterpret_cast<const short8*>(&As[(mrow + m) * 72 + kq]);
        short8 a1 = *reinterpret_cast<const short8*>(&As[(mrow + m) * 72 + kq + 32]);
        #pragma unroll
        for (int nt = 0; nt < 2; nt++) {
            int bo = (ngrp * 32 + nt * 16 + m) * 72 + kq;
            short8 b0 = *reinterpret_cast<const short8*>(&Bt[bo]);
            short8 b1 = *reinterpret_cast<const short8*>(&Bt[bo + 32]);
            acc[nt] = __builtin_amdgcn_mfma_f32_16x16x32_bf16(a0, b0, acc[nt], 0, 0, 0);
            acc[nt] = __builtin_amdgcn_mfma_f32_16x16x32_bf16(a1, b1, acc[nt], 0, 0, 0);
        }
    }
    // epilogue: bias + PE in registers, LN stats via shuffle + tiny LDS exchange
    float val[2][4];
    float s1r[4] = {0.f,0.f,0.f,0.f}, s2r[4] = {0.f,0.f,0.f,0.f};
    #pragma unroll
    for (int nt = 0; nt < 2; nt++) {
        int col = ngrp * 32 + nt * 16 + m;
        float bv = bias[col];
        float div = expf(-(float)(col & ~1) * 0.071955784f);
        #pragma unroll
        for (int r = 0; r < 4; r++) {
            int row = row0 + mrow + quad * 4 + r;
            int t = row & (SEQ - 1);
            float arg = (float)t * div;
            float pe = (col & 1) ? cosf(arg) : sinf(arg);
            float v = acc[nt][r] + bv + pe;
            val[nt][r] = v;
            s1r[r] += v; s2r[r] += v * v;
        }
    }
    #pragma unroll
    for (int o = 1; o < 16; o <<= 1) {
        #pragma unroll
        for (int r = 0; r < 4; r++) {
            s1r[r] += __shfl_xor(s1r[r], o);
            s2r[r] += __shfl_xor(s2r[r], o);
        }
    }
    if (m == 0) {
        #pragma unroll
        for (int r = 0; r < 4; r++) {
            ps1[mrow + quad * 4 + r][ngrp] = s1r[r];
            ps2[mrow + quad * 4 + r][ngrp] = s2r[r];
        }
    }
    __syncthreads();
    #pragma unroll
    for (int r = 0; r < 4; r++) {
        int rl = mrow + quad * 4 + r;
        float s1 = ps1[rl][0] + ps1[rl][1] + ps1[rl][2] + ps1[rl][3];
        float s2 = ps2[rl][0] + ps2[rl][1] + ps2[rl][2] + ps2[rl][3];
        float mu = s1 * (1.f / 128.f);
        float rs = rsqrtf(s2 * (1.f / 128.f) - mu * mu + 1e-5f);
        int row = row0 + rl;
        #pragma unroll
        for (int nt = 0; nt < 2; nt++) {
            int col = ngrp * 32 + nt * 16 + m;
            float v = val[nt][r];
            h[(size_t)row * DM + col] = v;
            hnb[(size_t)row * DM + col] = f2b((v - mu) * rs * lnw0[col] + lnb0[col]);
        }
    }
}

// ---------------- in_proj: z->bf16 zb, xBC->bf16, dt->softplus->dtb ----------------
__global__ __launch_bounds__(512) void inproj_mfma(const short* __restrict__ hnb,
                                                   const short* __restrict__ wb,
                                                   short* __restrict__ zb,
                                                   short* __restrict__ xbc,
                                                   float* __restrict__ dtb,
                                                   const float* __restrict__ dt_bias, int layer) {
    __shared__ short As[64 * 72];
    __shared__ short Bt[128 * 72];
    GEMM_PROLOGUE();
    int row0 = blockIdx.x * 64;
    int ncol0 = blockIdx.y * 128;
    const short* wt = wb + WB_IN + (size_t)layer * 82432;
    for (int kt = 0; kt < 2; kt++) {
        int k0 = kt * 64;
        if (kt) __syncthreads();
        *reinterpret_cast<short8*>(&As[ar * 72 + ak]) =
            *reinterpret_cast<const short8*>(&hnb[(size_t)(row0 + ar) * DM + k0 + ak]);
        #pragma unroll
        for (int i = 0; i < 2; i++) {
            int idx = tid + i * 512;
            int n = idx >> 3, kk = (idx & 7) * 8;
            int col = ncol0 + n;
            short8 bv = (short8)0;
            if (col < DIP) bv = *reinterpret_cast<const short8*>(&wt[col * 128 + k0 + kk]);
            *reinterpret_cast<short8*>(&Bt[n * 72 + kk]) = bv;
        }
        __syncthreads();
        GEMM_COMPUTE_TILE();
    }
    #pragma unroll
    for (int nt = 0; nt < 4; nt++) {
        int col = ncol0 + ngrp * 64 + nt * 16 + m;
        if (col < DI) {
            #pragma unroll
            for (int r = 0; r < 4; r++) {
                int row = row0 + mrow + (lane >> 4) * 4 + r;
                zb[(size_t)row * DI + col] = f2b(acc[nt][r]);
            }
        } else if (col < DI + CDIM) {
            #pragma unroll
            for (int r = 0; r < 4; r++) {
                int row = row0 + mrow + (lane >> 4) * 4 + r;
                xbc[(size_t)row * CDIM + (col - DI)] = f2b(acc[nt][r]);
            }
        } else if (col < DIP) {
            int hh = col - DI - CDIM;
            float db = dt_bias[layer * NH + hh];
            #pragma unroll
            for (int r = 0; r < 4; r++) {
                int row = row0 + mrow + (lane >> 4) * 4 + r;
                float raw = acc[nt][r] + db;
                float dt = (raw > 20.f) ? raw : log1pf(expf(raw));
                dtb[(size_t)row * NH + hh] = dt;
            }
        }
    }
}

// ---------------- causal conv(4) + SiLU, 4 tokens/block (bf16 in/out) ----------------
__global__ void conv_kernel(const short* __restrict__ xbc,
                            const float* __restrict__ convw, const float* __restrict__ convb,
                            short* __restrict__ xcb, int layer) {
    int c = threadIdx.x;            // 384
    int row0 = blockIdx.x * 4;
    int l0 = row0 & (SEQ - 1);
    const float* cw = convw + (size_t)layer * 4 * CDIM;
    float w0 = cw[c], w1 = cw[CDIM + c], w2 = cw[2 * CDIM + c], w3 = cw[3 * CDIM + c];
    float bb = convb[layer * CDIM + c];
    float v[7];
    #pragma unroll
    for (int i = 0; i < 7; i++) {
        int rr = row0 + i - 3;
        v[i] = (l0 + i - 3 >= 0) ? s2f(xbc[(size_t)rr * CDIM + c]) : 0.f;
    }
    #pragma unroll
    for (int j = 0; j < 4; j++) {
        float acc = bb + w0 * v[j] + w1 * v[j + 1] + w2 * v[j + 2] + w3 * v[j + 3];
        xcb[(size_t)(row0 + j) * CDIM + c] = f2b(silu(acc));
    }
}

// ---------------- chunk A (MFMA): S[p][n] -> bf16 ----------------
__global__ __launch_bounds__(256) void chunk_state_mfma(const short* __restrict__ xcb,
                                                        const float* __restrict__ dtb,
                                                        const float* __restrict__ A_log,
                                                        short* __restrict__ Slocb,
                                                        float* __restrict__ decay, int layer) {
    __shared__ short XTw[64 * 72];   // [p][t]
    __shared__ short BT[64 * 72];    // [n][t]
    __shared__ float wst[64];
    int bid = blockIdx.x;
    int c  = bid & (NCHUNK - 1);
    int hh = (bid >> 4) & (NH - 1);
    int b  = bid >> 6;
    int tid = threadIdx.x;
    int row0 = b * SEQ + c * CHUNK;
    float A = -expf(A_log[layer * NH + hh]);

    if (tid < CHUNK) {
        float dtv = dtb[(size_t)(row0 + tid) * NH + hh];
        float l = dtv * A;
        #pragma unroll
        for (int o = 1; o < 64; o <<= 1) { float v = __shfl_up(l, o); if (tid >= o) l += v; }
        float Ltot = __shfl(l, 63);
        wst[tid] = expf(Ltot - l) * dtv;
        if (tid == 63) decay[bid] = expf(Ltot);
    }
    __syncthreads();
    {
        int p = tid & 63;
        int tb0 = tid >> 6;
        #pragma unroll
        for (int i = 0; i < 2; i++) {
            int t0 = (tb0 + i * 4) * 8;
            short8 xv, bv;
            #pragma unroll
            for (int j = 0; j < 8; j++) {
                int t = t0 + j;
                const short* xr = xcb + (size_t)(row0 + t) * CDIM;
                xv[j] = f2b(s2f(xr[hh * HD + p]) * wst[t]);
                bv[j] = xr[DI + p];
            }
            *reinterpret_cast<short8*>(&XTw[p * 72 + t0]) = xv;
            *reinterpret_cast<short8*>(&BT[p * 72 + t0]) = bv;
        }
    }
    __syncthreads();

    int lane = tid & 63;
    int m = lane & 15;
    int kq = (lane >> 4) * 8;
    int w = tid >> 6;
    int a_off = (w * 16 + m) * 72 + kq;
    float4v acc[4];
    acc[0] = (float4v)0.f; acc[1] = (float4v)0.f; acc[2] = (float4v)0.f; acc[3] = (float4v)0.f;
    short8 a0 = *reinterpret_cast<const short8*>(&XTw[a_off]);
    short8 a1 = *reinterpret_cast<const short8*>(&XTw[a_off + 32]);
    #pragma unroll
    for (int nt = 0; nt < 4; nt++) {
        int bo = (nt * 16 + m) * 72 + kq;
        short8 b0 = *reinterpret_cast<const short8*>(&BT[bo]);
        short8 b1 = *reinterpret_cast<const short8*>(&BT[bo + 32]);
        acc[nt] = __builtin_amdgcn_mfma_f32_16x16x32_bf16(a0, b0, acc[nt], 0, 0, 0);
        acc[nt] = __builtin_amdgcn_mfma_f32_16x16x32_bf16(a1, b1, acc[nt], 0, 0, 0);
    }
    short* Sp = Slocb + (size_t)bid * (HD * DST);
    int tq = (lane >> 4) * 4;
    #pragma unroll
    for (int nt = 0; nt < 4; nt++) {
        #pragma unroll
        for (int r = 0; r < 4; r++) {
            int p = w * 16 + tq + r;
            int n = nt * 16 + m;
            Sp[p * DST + n] = f2b(acc[nt][r]);   // [p][n] bf16
        }
    }
}

// ---------------- chunk C (MFMA) + fused inter-chunk recurrence: outputs -> y bf16 ----------------
__global__ __launch_bounds__(256) void chunk_out_mfma(const short* __restrict__ xcb,
                                                      const float* __restrict__ dtb,
                                                      const float* __restrict__ A_log,
                                                      const float* __restrict__ Dpw,
                                                      const short* __restrict__ Slocb,
                                                      const float* __restrict__ decay,
                                                      short* __restrict__ ybb, int layer) {
    __shared__ short Cb[64 * 72];    // [t][n]
    __shared__ short Bb[64 * 72];    // [s][n], later M[t][s]
    __shared__ short XT[64 * 72];    // [p][t]
    __shared__ short HT[64 * 72];    // [p][n]
    __shared__ float Ls[64], dts[64];
    int bid = blockIdx.x;
    int c  = bid & (NCHUNK - 1);
    int hh = (bid >> 4) & (NH - 1);
    int b  = bid >> 6;
    int tid = threadIdx.x;
    int row0 = b * SEQ + c * CHUNK;
    int bh0 = bid & ~(NCHUNK - 1);      // base bid for chunk 0 of this (b,h)
    float A = -expf(A_log[layer * NH + hh]);
    float Dph = Dpw[layer * NH + hh];

    if (tid < CHUNK) {
        float dtv = dtb[(size_t)(row0 + tid) * NH + hh];
        float l = dtv * A;
        #pragma unroll
        for (int o = 1; o < 64; o <<= 1) { float v = __shfl_up(l, o); if (tid >= o) l += v; }
        Ls[tid] = l;
        dts[tid] = dtv;
    }
    // --- fused inter-chunk recurrence: hstart = sum_{j<c} (prod d) S_j, in registers ---
    {
        float hreg[16];
        #pragma unroll
        for (int k = 0; k < 16; k++) hreg[k] = 0.f;
        for (int j = 0; j < c; j++) {
            float d = decay[bh0 + j];
            const short* Sp = Slocb + (size_t)(bh0 + j) * (HD * DST) + tid * 16;
            short8 s0 = *reinterpret_cast<const short8*>(Sp);
            short8 s1 = *reinterpret_cast<const short8*>(Sp + 8);
            #pragma unroll
            for (int k = 0; k < 8; k++) {
                hreg[k]     = d * hreg[k]     + s2f(s0[k]);
                hreg[8 + k] = d * hreg[8 + k] + s2f(s1[k]);
            }
        }
        // thread owns p = tid>>2, n0 = (tid&3)*16
        int p = tid >> 2;
        int n0 = (tid & 3) * 16;
        short8 h0, h1;
        #pragma unroll
        for (int k = 0; k < 8; k++) { h0[k] = f2b(hreg[k]); h1[k] = f2b(hreg[8 + k]); }
        *reinterpret_cast<short8*>(&HT[p * 72 + n0]) = h0;
        *reinterpret_cast<short8*>(&HT[p * 72 + n0 + 8]) = h1;
    }
    {
        int p = tid & 63;
        int tb0 = tid >> 6;
        #pragma unroll
        for (int i = 0; i < 2; i++) {
            int t0 = (tb0 + i * 4) * 8;
            short8 xv;
            #pragma unroll
            for (int j = 0; j < 8; j++)
                xv[j] = xcb[(size_t)(row0 + t0 + j) * CDIM + hh * HD + p];
            *reinterpret_cast<short8*>(&XT[p * 72 + t0]) = xv;
        }
    }
    #pragma unroll
    for (int i = 0; i < 2; i++) {   // Bb, Cb: direct bf16 copies
        int idx = tid + i * 256;
        int t = idx >> 3, cb = (idx & 7) * 8;
        const short* xr = xcb + (size_t)(row0 + t) * CDIM;
        *reinterpret_cast<short8*>(&Bb[t * 72 + cb]) =
            *reinterpret_cast<const short8*>(&xr[DI + cb]);
        *reinterpret_cast<short8*>(&Cb[t * 72 + cb]) =
            *reinterpret_cast<const short8*>(&xr[DI + DST + cb]);
    }
    __syncthreads();

    int lane = tid & 63;
    int m = lane & 15;
    int kq = (lane >> 4) * 8;
    int w = tid >> 6;
    int tq = (lane >> 4) * 4;
    int a_off = (w * 16 + m) * 72 + kq;

    short8 ca0 = *reinterpret_cast<const short8*>(&Cb[a_off]);
    short8 ca1 = *reinterpret_cast<const short8*>(&Cb[a_off + 32]);

    float4v g[4], ir[4];
    #pragma unroll
    for (int i = 0; i < 4; i++) { g[i] = (float4v)0.f; ir[i] = (float4v)0.f; }
    #pragma unroll
    for (int st = 0; st < 4; st++) {
        int bo = (st * 16 + m) * 72 + kq;
        short8 b0 = *reinterpret_cast<const short8*>(&Bb[bo]);
        short8 b1 = *reinterpret_cast<const short8*>(&Bb[bo + 32]);
        g[st] = __builtin_amdgcn_mfma_f32_16x16x32_bf16(ca0, b0, g[st], 0, 0, 0);
        g[st] = __builtin_amdgcn_mfma_f32_16x16x32_bf16(ca1, b1, g[st], 0, 0, 0);
        short8 h0 = *reinterpret_cast<const short8*>(&HT[bo]);
        short8 h1 = *reinterpret_cast<const short8*>(&HT[bo + 32]);
        ir[st] = __builtin_amdgcn_mfma_f32_16x16x32_bf16(ca0, h0, ir[st], 0, 0, 0);
        ir[st] = __builtin_amdgcn_mfma_f32_16x16x32_bf16(ca1, h1, ir[st], 0, 0, 0);
    }
    __syncthreads();
    #pragma unroll
    for (int st = 0; st < 4; st++) {
        #pragma unroll
        for (int r = 0; r < 4; r++) {
            int t = w * 16 + tq + r;
            int s = st * 16 + m;
            float mv = 0.f;
            if (s <= t) mv = g[st][r] * expf(Ls[t] - Ls[s]) * dts[s];
            Bb[t * 72 + s] = f2b(mv);
        }
    }
    __syncthreads();
    float4v yi[4];
    #pragma unroll
    for (int i = 0; i < 4; i++) yi[i] = (float4v)0.f;
    short8 ma0 = *reinterpret_cast<const short8*>(&Bb[a_off]);
    short8 ma1 = *reinterpret_cast<const short8*>(&Bb[a_off + 32]);
    #pragma unroll
    for (int pt = 0; pt < 4; pt++) {
        int bo = (pt * 16 + m) * 72 + kq;
        short8 x0 = *reinterpret_cast<const short8*>(&XT[bo]);
        short8 x1 = *reinterpret_cast<const short8*>(&XT[bo + 32]);
        yi[pt] = __builtin_amdgcn_mfma_f32_16x16x32_bf16(ma0, x0, yi[pt], 0, 0, 0);
        yi[pt] = __builtin_amdgcn_mfma_f32_16x16x32_bf16(ma1, x1, yi[pt], 0, 0, 0);
    }
    #pragma unroll
    for (int r = 0; r < 4; r++) {
        int t = w * 16 + tq + r;
        float et = expf(Ls[t]);
        short* yr = ybb + (size_t)(row0 + t) * DI + hh * HD;
        #pragma unroll
        for (int pt = 0; pt < 4; pt++) {
            int p = pt * 16 + m;
            float xv = s2f(XT[p * 72 + t]);
            yr[p] = f2b(yi[pt][r] + et * ir[pt][r] + Dph * xv);
        }
    }
}

// ---------------- out_proj + gate/RMSNorm + residual + fused next-layer LN ----------------
__global__ __launch_bounds__(512) void outproj_gate_mfma(const short* __restrict__ ybb,
                                                         const short* __restrict__ zb,
                                                         const float* __restrict__ rmsw,
                                                         const short* __restrict__ wb,
                                                         const float* __restrict__ lnw2,
                                                         const float* __restrict__ lnb2,
                                                         float* __restrict__ h,
                                                         short* __restrict__ hnb,
                                                         int layer, int write_hn) {
    __shared__ __align__(16) char smem[64 * 133 * 4];
    short* As = (short*)smem;
    short* Bt = (short*)(smem + 64 * 72 * 2);
    float* hs = (float*)smem;                  // overlaid
    __shared__ float rs_s[64];
    GEMM_PROLOGUE();
    int row0 = blockIdx.x * 64;
    const short* wt = wb + WB_OUT + (size_t)layer * 32768;
    {   // RMS stats on v = y*silu(z): 8 threads/row, 32 cols each
        int r = tid >> 3, j = tid & 7;
        const short8* yr = (const short8*)(ybb + (size_t)(row0 + r) * DI + j * 32);
        const short8* zr = (const short8*)(zb + (size_t)(row0 + r) * DI + j * 32);
        float s2 = 0.f;
        #pragma unroll
        for (int i = 0; i < 4; i++) {
            short8 yv = yr[i];
            short8 zv = zr[i];
            #pragma unroll
            for (int q = 0; q < 8; q++) {
                float v = s2f(yv[q]) * silu(s2f(zv[q]));
                s2 += v * v;
            }
        }
        #pragma unroll
        for (int o = 1; o < 8; o <<= 1) s2 += __shfl_xor(s2, o);
        if (j == 0) rs_s[r] = rsqrtf(s2 * (1.f / 256.f) + 1e-5f);
    }
    __syncthreads();
    for (int kt = 0; kt < 4; kt++) {
        int k0 = kt * 64;
        if (kt) __syncthreads();
        {
            int k = k0 + ak;
            short8 yv = *(const short8*)(ybb + (size_t)(row0 + ar) * DI + k);
            short8 zv = *(const short8*)(zb + (size_t)(row0 + ar) * DI + k);
            float4 w0 = *(const float4*)(rmsw + layer * DI + k);
            float4 w1 = *(const float4*)(rmsw + layer * DI + k + 4);
            float rs = rs_s[ar];
            short8 av;
            av[0] = f2b(s2f(yv[0]) * silu(s2f(zv[0])) * rs * w0.x);
            av[1] = f2b(s2f(yv[1]) * silu(s2f(zv[1])) * rs * w0.y);
            av[2] = f2b(s2f(yv[2]) * silu(s2f(zv[2])) * rs * w0.z);
            av[3] = f2b(s2f(yv[3]) * silu(s2f(zv[3])) * rs * w0.w);
            av[4] = f2b(s2f(yv[4]) * silu(s2f(zv[4])) * rs * w1.x);
            av[5] = f2b(s2f(yv[5]) * silu(s2f(zv[5])) * rs * w1.y);
            av[6] = f2b(s2f(yv[6]) * silu(s2f(zv[6])) * rs * w1.z);
            av[7] = f2b(s2f(yv[7]) * silu(s2f(zv[7])) * rs * w1.w);
            *reinterpret_cast<short8*>(&As[ar * 72 + ak]) = av;
        }
        GEMM_STAGE_B(wt, 256, k0);
        __syncthreads();
        GEMM_COMPUTE_TILE();
    }
    __syncthreads();   // done with As/Bt; reuse as hs
    #pragma unroll
    for (int nt = 0; nt < 4; nt++) {
        int col = ngrp * 64 + nt * 16 + m;
        #pragma unroll
        for (int r = 0; r < 4; r++) {
            int rr = mrow + (lane >> 4) * 4 + r;
            hs[rr * 133 + col] = acc[nt][r];
        }
    }
    __syncthreads();
    {   // residual add + LN + stores
        int r = tid >> 3, j = tid & 7;
        int row = row0 + r;
        float* hdst = h + (size_t)row * DM + j * 16;
        float vals[16]; float s1 = 0.f, s2 = 0.f;
        #pragma unroll
        for (int i = 0; i < 4; i++) {
            float4 ho = *(const float4*)(hdst + i * 4);
            float v0 = ho.x + hs[r * 133 + j * 16 + i * 4];
            float v1 = ho.y + hs[r * 133 + j * 16 + i * 4 + 1];
            float v2 = ho.z + hs[r * 133 + j * 16 + i * 4 + 2];
            float v3 = ho.w + hs[r * 133 + j * 16 + i * 4 + 3];
            vals[i*4] = v0; vals[i*4+1] = v1; vals[i*4+2] = v2; vals[i*4+3] = v3;
            s1 += v0 + v1 + v2 + v3;
            s2 += v0*v0 + v1*v1 + v2*v2 + v3*v3;
        }
        #pragma unroll
        for (int o = 1; o < 8; o <<= 1) { s1 += __shfl_xor(s1, o); s2 += __shfl_xor(s2, o); }
        #pragma unroll
        for (int i = 0; i < 4; i++)
            *(float4*)(hdst + i * 4) = make_float4(vals[i*4], vals[i*4+1], vals[i*4+2], vals[i*4+3]);
        if (write_hn) {
            float mu = s1 * (1.f / 128.f);
            float rs = rsqrtf(s2 * (1.f / 128.f) - mu * mu + 1e-5f);
            const float* lw = lnw2 + j * 16;
            const float* lb = lnb2 + j * 16;
            short8 a0, a1;
            #pragma unroll
            for (int i = 0; i < 8; i++) {
                a0[i] = f2b((vals[i] - mu) * rs * lw[i] + lb[i]);
                a1[i] = f2b((vals[8 + i] - mu) * rs * lw[8 + i] + lb[8 + i]);
            }
            short* hndst = hnb + (size_t)row * DM + j * 16;
            *reinterpret_cast<short8*>(hndst) = a0;
            *reinterpret_cast<short8*>(hndst + 8) = a1;
        }
    }
}

// ---------------- fc2a + fc2b fused ----------------
__global__ __launch_bounds__(512) void fc2ab_mfma(const float* __restrict__ h,
                                                  const short* __restrict__ wb,
                                                  const float* __restrict__ b1,
                                                  const float* __restrict__ W2,
                                                  const float* __restrict__ b2,
                                                  float* __restrict__ out) {
    __shared__ short As[64 * 72];
    __shared__ short Bt[128 * 72];
    __shared__ float h2s[64][132];
    __shared__ float w2s[768];
    GEMM_PROLOGUE();
    int row0 = blockIdx.x * 64;
    const short* wt = wb + WB_FC2;
    for (int i = tid; i < 768; i += 512) w2s[i] = W2[i];
    for (int kt = 0; kt < 2; kt++) {
        int k0 = kt * 64;
        if (kt) __syncthreads();
        {
            const float* src = h + (size_t)(row0 + ar) * DM + k0 + ak;
            float4 v0 = *(const float4*)src;
            float4 v1 = *(const float4*)(src + 4);
            *reinterpret_cast<short8*>(&As[ar * 72 + ak]) = pack8f(v0, v1);
        }
        GEMM_STAGE_B(wt, 128, k0);
        __syncthreads();
        GEMM_COMPUTE_TILE();
    }
    #pragma unroll
    for (int nt = 0; nt < 4; nt++) {
        int col = ngrp * 64 + nt * 16 + m;
        float bv = b1[col];
        #pragma unroll
        for (int r = 0; r < 4; r++) {
            int rr = mrow + (lane >> 4) * 4 + r;
            float o = acc[nt][r] + bv;
            h2s[rr][col] = (o > 0.f) ? o : 0.1f * o;
        }
    }
    __syncthreads();
    if (tid < 384) {
        int r = tid / 6, cc = tid % 6;
        float acc2 = b2[cc];
        #pragma unroll 16
        for (int k = 0; k < 128; k++) acc2 += h2s[r][k] * w2s[k * 6 + cc];
        out[(size_t)(row0 + r) * 6 + cc] = acc2;
    }
}

extern "C" void kernel_launch(void* const* d_in, const int* in_sizes, int n_in,
                              void* d_out, int out_size, void* d_ws, size_t ws_size,
                              hipStream_t stream) {
    const float* x       = (const float*)d_in[0];
    const float* fc1_W   = (const float*)d_in[1];
    const float* fc1_b   = (const float*)d_in[2];
    const float* ln_w    = (const float*)d_in[3];
    const float* ln_b    = (const float*)d_in[4];
    const float* in_W    = (const float*)d_in[5];
    const float* conv_w  = (const float*)d_in[6];
    const float* conv_b  = (const float*)d_in[7];
    const float* dt_bias = (const float*)d_in[8];
    const float* A_log   = (const float*)d_in[9];
    const float* Dp      = (const float*)d_in[10];
    const float* rms_w   = (const float*)d_in[11];
    const float* out_W   = (const float*)d_in[12];
    const float* fc2_W1  = (const float*)d_in[13];
    const float* fc2_b1  = (const float*)d_in[14];
    const float* fc2_W2  = (const float*)d_in[15];
    const float* fc2_b2  = (const float*)d_in[16];
    float* out = (float*)d_out;

    float* ws = (float*)d_ws;
    float* h     = ws;                            // NROWS*DM f32
    float* dtb   = h     + (size_t)NROWS * DM;    // NROWS*NH f32
    float* decay = dtb   + (size_t)NROWS * NH;    // 1024 f32
    short* sbase = (short*)(decay + 1024);
    short* hnb   = sbase;                          // NROWS*DM sh
    short* zb    = hnb   + (size_t)NROWS * DM;     // NROWS*DI sh
    short* xbc   = zb    + (size_t)NROWS * DI;     // NROWS*CDIM sh
    short* xcb   = xbc   + (size_t)NROWS * CDIM;   // NROWS*CDIM sh
    short* ybb   = xcb   + (size_t)NROWS * CDIM;   // NROWS*DI sh
    short* Slocb = ybb   + (size_t)NROWS * DI;     // 1024*4096 sh
    short* wb    = Slocb + (size_t)BATCH*NH*NCHUNK*HD*DST;

    prep_weights<<<1348, 256, 0, stream>>>(fc1_W, in_W, out_W, fc2_W1, wb);
    fc1_mfma<<<NROWS / 32, 512, 0, stream>>>(x, wb + WB_FC1, fc1_b, ln_w, ln_b, h, hnb);

    for (int layer = 0; layer < 2; layer++) {
        inproj_mfma<<<dim3(NROWS / 64, 6), 512, 0, stream>>>(hnb, wb, zb, xbc, dtb,
                                                             dt_bias, layer);
        conv_kernel<<<NROWS / 4, CDIM, 0, stream>>>(xbc, conv_w, conv_b, xcb, layer);
        chunk_state_mfma<<<BATCH*NH*NCHUNK, 256, 0, stream>>>(xcb, dtb, A_log, Slocb, decay, layer);
        chunk_out_mfma<<<BATCH*NH*NCHUNK, 256, 0, stream>>>(xcb, dtb, A_log, Dp, Slocb, decay,
                                                            ybb, layer);
        outproj_gate_mfma<<<NROWS / 64, 512, 0, stream>>>(ybb, zb, rms_w, wb,
                                                          ln_w + DM, ln_b + DM, h, hnb,
                                                          layer, layer == 0 ? 1 : 0);
    }

    fc2ab_mfma<<<NROWS / 64, 512, 0, stream>>>(h, wb, fc2_b1, fc2_W2, fc2_b2, out);
}

// Round 15
// 255.917 us; speedup vs baseline: 1.0773x; 1.0159x over previous
//
#include <hip/hip_runtime.h>
#include <hip/hip_bf16.h>

// Dims
#define BATCH 16
#define SEQ 1024
#define NROWS (BATCH*SEQ)          // 16384 tokens
#define IN_DIM 768
#define DM 128
#define DIP 644
#define DI 256
#define CDIM 384
#define DST 64
#define NH 4
#define HD 64
#define CHUNK 64
#define NCHUNK (SEQ/CHUNK)         // 16

// bf16 weight area offsets (in shorts)
#define WB_FC1   0          // [128][768]
#define WB_IN    98304      // [2][644][128]
#define WB_OUT   263168     // [2][128][256]
#define WB_FC2   328704     // [128][128]
#define WB_TOTAL 345088

typedef __attribute__((ext_vector_type(8))) short short8;
typedef __attribute__((ext_vector_type(4))) float float4v;

// f32 -> bf16 (RNE) as raw short
__device__ __forceinline__ short f2b(float f) {
    unsigned u = __builtin_bit_cast(unsigned, f);
    u += 0x7fffu + ((u >> 16) & 1u);
    return (short)(u >> 16);
}
__device__ __forceinline__ float s2f(short s) {
    unsigned u = ((unsigned)(unsigned short)s) << 16;
    return __builtin_bit_cast(float, u);
}
__device__ __forceinline__ short8 pack8f(float4 a, float4 b) {
    short8 r;
    r[0] = f2b(a.x); r[1] = f2b(a.y); r[2] = f2b(a.z); r[3] = f2b(a.w);
    r[4] = f2b(b.x); r[5] = f2b(b.y); r[6] = f2b(b.z); r[7] = f2b(b.w);
    return r;
}
__device__ __forceinline__ float silu(float a) { return a / (1.f + expf(-a)); }

// ---------------- weight prep: convert + transpose to bf16 ----------------
__global__ void prep_weights(const float* __restrict__ fc1_W, const float* __restrict__ in_W,
                             const float* __restrict__ out_W, const float* __restrict__ fc2_W1,
                             short* __restrict__ wb) {
    int idx = blockIdx.x * 256 + threadIdx.x;
    if (idx < 98304) {                       // fc1_Wt[n][k] <- fc1_W[k][n]
        int n = idx / 768, k = idx % 768;
        wb[WB_FC1 + idx] = f2b(fc1_W[k * 128 + n]);
        return;
    }
    idx -= 98304;
    if (idx < 2 * 82432) {                   // in_Wt[l][n][k] <- in_W[l][k][n]
        int l = idx / 82432, r = idx % 82432;
        int n = r / 128, k = r % 128;
        wb[WB_IN + idx] = f2b(in_W[(size_t)l * 82432 + k * 644 + n]);
        return;
    }
    idx -= 164864;
    if (idx < 2 * 32768) {                   // out_Wt[l][n][k] <- out_W[l][k][n]
        int l = idx / 32768, r = idx % 32768;
        int n = r / 256, k = r % 256;
        wb[WB_OUT + idx] = f2b(out_W[(size_t)l * 32768 + k * 128 + n]);
        return;
    }
    idx -= 65536;
    if (idx < 16384) {                       // fc2_W1t[n][k] <- fc2_W1[k][n]
        int n = idx / 128, k = idx % 128;
        wb[WB_FC2 + idx] = f2b(fc2_W1[k * 128 + n]);
    }
}

// ============================================================
// MFMA GEMM tile pattern (block 512 = 8 waves, M=64 x N=128)
// ============================================================
#define GEMM_PROLOGUE() \
    int tid = threadIdx.x; \
    int lane = tid & 63; \
    int m = lane & 15; \
    int kq = (lane >> 4) * 8; \
    int w = tid >> 6; \
    int mrow = (w & 3) * 16; \
    int ngrp = w >> 2; \
    int a_off = (mrow + m) * 72 + kq; \
    int b_off = (ngrp * 64 + m) * 72 + kq; \
    int ar = tid >> 3; \
    int ak = (tid & 7) * 8; \
    (void)ar; (void)ak; \
    float4v acc[4]; \
    acc[0] = (float4v)0.f; acc[1] = (float4v)0.f; acc[2] = (float4v)0.f; acc[3] = (float4v)0.f;

#define GEMM_COMPUTE_TILE() \
    { \
        short8 a0 = *reinterpret_cast<const short8*>(&As[a_off]); \
        short8 a1 = *reinterpret_cast<const short8*>(&As[a_off + 32]); \
        _Pragma("unroll") \
        for (int nt = 0; nt < 4; nt++) { \
            short8 b0 = *reinterpret_cast<const short8*>(&Bt[b_off + nt * 16 * 72]); \
            short8 b1 = *reinterpret_cast<const short8*>(&Bt[b_off + nt * 16 * 72 + 32]); \
            acc[nt] = __builtin_amdgcn_mfma_f32_16x16x32_bf16(a0, b0, acc[nt], 0, 0, 0); \
            acc[nt] = __builtin_amdgcn_mfma_f32_16x16x32_bf16(a1, b1, acc[nt], 0, 0, 0); \
        } \
    }

#define GEMM_STAGE_B(wtptr, LDB, k0) \
    _Pragma("unroll") \
    for (int i = 0; i < 2; i++) { \
        int idx = tid + i * 512; \
        int n = idx >> 3, kk = (idx & 7) * 8; \
        *reinterpret_cast<short8*>(&Bt[n * 72 + kk]) = \
            *reinterpret_cast<const short8*>(&wtptr[n * (LDB) + (k0) + kk]); \
    }

// ---------------- fc1 (MFMA, M=32, 512thr, 512 blocks) + PE + register-LN ----------------
__global__ __launch_bounds__(512) void fc1_mfma(const float* __restrict__ x,
                                                const short* __restrict__ wt,
                                                const float* __restrict__ bias,
                                                const float* __restrict__ lnw0,
                                                const float* __restrict__ lnb0,
                                                float* __restrict__ h,
                                                short* __restrict__ hnb) {
    __shared__ short As[32 * 72];
    __shared__ short Bt[128 * 72];
    __shared__ float ps1[32][4], ps2[32][4];
    int tid = threadIdx.x;
    int lane = tid & 63;
    int m = lane & 15;
    int quad = lane >> 4;
    int kq = quad * 8;
    int w = tid >> 6;              // 0..7
    int mrow = (w & 1) * 16;
    int ngrp = w >> 1;             // 0..3 -> cols ngrp*32 .. +31
    int ar = tid >> 4;             // 0..31
    int ac = (tid & 15) * 4;       // 0..60
    int row0 = blockIdx.x * 32;
    float4v acc[2];
    acc[0] = (float4v)0.f; acc[1] = (float4v)0.f;
    for (int kt = 0; kt < 12; kt++) {
        int k0 = kt * 64;
        if (kt) __syncthreads();
        {
            const float* src = x + (size_t)(row0 + ar) * IN_DIM + k0 + ac;
            float4 v = *(const float4*)src;
            short4 pv;
            pv.x = f2b(v.x); pv.y = f2b(v.y); pv.z = f2b(v.z); pv.w = f2b(v.w);
            *reinterpret_cast<short4*>(&As[ar * 72 + ac]) = pv;
        }
        GEMM_STAGE_B(wt, 768, k0);
        __syncthreads();
        short8 a0 = *reinterpret_cast<const short8*>(&As[(mrow + m) * 72 + kq]);
        short8 a1 = *reinterpret_cast<const short8*>(&As[(mrow + m) * 72 + kq + 32]);
        #pragma unroll
        for (int nt = 0; nt < 2; nt++) {
            int bo = (ngrp * 32 + nt * 16 + m) * 72 + kq;
            short8 b0 = *reinterpret_cast<const short8*>(&Bt[bo]);
            short8 b1 = *reinterpret_cast<const short8*>(&Bt[bo + 32]);
            acc[nt] = __builtin_amdgcn_mfma_f32_16x16x32_bf16(a0, b0, acc[nt], 0, 0, 0);
            acc[nt] = __builtin_amdgcn_mfma_f32_16x16x32_bf16(a1, b1, acc[nt], 0, 0, 0);
        }
    }
    float val[2][4];
    float s1r[4] = {0.f,0.f,0.f,0.f}, s2r[4] = {0.f,0.f,0.f,0.f};
    #pragma unroll
    for (int nt = 0; nt < 2; nt++) {
        int col = ngrp * 32 + nt * 16 + m;
        float bv = bias[col];
        float div = expf(-(float)(col & ~1) * 0.071955784f);
        #pragma unroll
        for (int r = 0; r < 4; r++) {
            int row = row0 + mrow + quad * 4 + r;
            int t = row & (SEQ - 1);
            float arg = (float)t * div;
            float pe = (col & 1) ? cosf(arg) : sinf(arg);
            float v = acc[nt][r] + bv + pe;
            val[nt][r] = v;
            s1r[r] += v; s2r[r] += v * v;
        }
    }
    #pragma unroll
    for (int o = 1; o < 16; o <<= 1) {
        #pragma unroll
        for (int r = 0; r < 4; r++) {
            s1r[r] += __shfl_xor(s1r[r], o);
            s2r[r] += __shfl_xor(s2r[r], o);
        }
    }
    if (m == 0) {
        #pragma unroll
        for (int r = 0; r < 4; r++) {
            ps1[mrow + quad * 4 + r][ngrp] = s1r[r];
            ps2[mrow + quad * 4 + r][ngrp] = s2r[r];
        }
    }
    __syncthreads();
    #pragma unroll
    for (int r = 0; r < 4; r++) {
        int rl = mrow + quad * 4 + r;
        float s1 = ps1[rl][0] + ps1[rl][1] + ps1[rl][2] + ps1[rl][3];
        float s2 = ps2[rl][0] + ps2[rl][1] + ps2[rl][2] + ps2[rl][3];
        float mu = s1 * (1.f / 128.f);
        float rs = rsqrtf(s2 * (1.f / 128.f) - mu * mu + 1e-5f);
        int row = row0 + rl;
        #pragma unroll
        for (int nt = 0; nt < 2; nt++) {
            int col = ngrp * 32 + nt * 16 + m;
            float v = val[nt][r];
            h[(size_t)row * DM + col] = v;
            hnb[(size_t)row * DM + col] = f2b((v - mu) * rs * lnw0[col] + lnb0[col]);
        }
    }
}

// ---------------- in_proj: z->bf16 zb, xBC->bf16, dt->softplus->dtb ----------------
__global__ __launch_bounds__(512) void inproj_mfma(const short* __restrict__ hnb,
                                                   const short* __restrict__ wb,
                                                   short* __restrict__ zb,
                                                   short* __restrict__ xbc,
                                                   float* __restrict__ dtb,
                                                   const float* __restrict__ dt_bias, int layer) {
    __shared__ short As[64 * 72];
    __shared__ short Bt[128 * 72];
    GEMM_PROLOGUE();
    int row0 = blockIdx.x * 64;
    int ncol0 = blockIdx.y * 128;
    const short* wt = wb + WB_IN + (size_t)layer * 82432;
    for (int kt = 0; kt < 2; kt++) {
        int k0 = kt * 64;
        if (kt) __syncthreads();
        *reinterpret_cast<short8*>(&As[ar * 72 + ak]) =
            *reinterpret_cast<const short8*>(&hnb[(size_t)(row0 + ar) * DM + k0 + ak]);
        #pragma unroll
        for (int i = 0; i < 2; i++) {
            int idx = tid + i * 512;
            int n = idx >> 3, kk = (idx & 7) * 8;
            int col = ncol0 + n;
            short8 bv = (short8)0;
            if (col < DIP) bv = *reinterpret_cast<const short8*>(&wt[col * 128 + k0 + kk]);
            *reinterpret_cast<short8*>(&Bt[n * 72 + kk]) = bv;
        }
        __syncthreads();
        GEMM_COMPUTE_TILE();
    }
    #pragma unroll
    for (int nt = 0; nt < 4; nt++) {
        int col = ncol0 + ngrp * 64 + nt * 16 + m;
        if (col < DI) {
            #pragma unroll
            for (int r = 0; r < 4; r++) {
                int row = row0 + mrow + (lane >> 4) * 4 + r;
                zb[(size_t)row * DI + col] = f2b(acc[nt][r]);
            }
        } else if (col < DI + CDIM) {
            #pragma unroll
            for (int r = 0; r < 4; r++) {
                int row = row0 + mrow + (lane >> 4) * 4 + r;
                xbc[(size_t)row * CDIM + (col - DI)] = f2b(acc[nt][r]);
            }
        } else if (col < DIP) {
            int hh = col - DI - CDIM;
            float db = dt_bias[layer * NH + hh];
            #pragma unroll
            for (int r = 0; r < 4; r++) {
                int row = row0 + mrow + (lane >> 4) * 4 + r;
                float raw = acc[nt][r] + db;
                float dt = (raw > 20.f) ? raw : log1pf(expf(raw));
                dtb[(size_t)row * NH + hh] = dt;
            }
        }
    }
}

// ---------------- causal conv(4) + SiLU, 4 tokens/block (bf16 in/out) ----------------
__global__ void conv_kernel(const short* __restrict__ xbc,
                            const float* __restrict__ convw, const float* __restrict__ convb,
                            short* __restrict__ xcb, int layer) {
    int c = threadIdx.x;            // 384
    int row0 = blockIdx.x * 4;
    int l0 = row0 & (SEQ - 1);
    const float* cw = convw + (size_t)layer * 4 * CDIM;
    float w0 = cw[c], w1 = cw[CDIM + c], w2 = cw[2 * CDIM + c], w3 = cw[3 * CDIM + c];
    float bb = convb[layer * CDIM + c];
    float v[7];
    #pragma unroll
    for (int i = 0; i < 7; i++) {
        int rr = row0 + i - 3;
        v[i] = (l0 + i - 3 >= 0) ? s2f(xbc[(size_t)rr * CDIM + c]) : 0.f;
    }
    #pragma unroll
    for (int j = 0; j < 4; j++) {
        float acc = bb + w0 * v[j] + w1 * v[j + 1] + w2 * v[j + 2] + w3 * v[j + 3];
        xcb[(size_t)(row0 + j) * CDIM + c] = f2b(silu(acc));
    }
}

// ---------------- chunk A (MFMA): S[p][n] -> bf16 ----------------
__global__ __launch_bounds__(256) void chunk_state_mfma(const short* __restrict__ xcb,
                                                        const float* __restrict__ dtb,
                                                        const float* __restrict__ A_log,
                                                        short* __restrict__ Slocb,
                                                        float* __restrict__ decay, int layer) {
    __shared__ short XTw[64 * 72];   // [p][t]
    __shared__ short BT[64 * 72];    // [n][t]
    __shared__ float wst[64];
    int bid = blockIdx.x;
    int c  = bid & (NCHUNK - 1);
    int hh = (bid >> 4) & (NH - 1);
    int b  = bid >> 6;
    int tid = threadIdx.x;
    int row0 = b * SEQ + c * CHUNK;
    float A = -expf(A_log[layer * NH + hh]);

    if (tid < CHUNK) {
        float dtv = dtb[(size_t)(row0 + tid) * NH + hh];
        float l = dtv * A;
        #pragma unroll
        for (int o = 1; o < 64; o <<= 1) { float v = __shfl_up(l, o); if (tid >= o) l += v; }
        float Ltot = __shfl(l, 63);
        wst[tid] = expf(Ltot - l) * dtv;
        if (tid == 63) decay[bid] = expf(Ltot);
    }
    __syncthreads();
    {
        int p = tid & 63;
        int tb0 = tid >> 6;
        #pragma unroll
        for (int i = 0; i < 2; i++) {
            int t0 = (tb0 + i * 4) * 8;
            short8 xv, bv;
            #pragma unroll
            for (int j = 0; j < 8; j++) {
                int t = t0 + j;
                const short* xr = xcb + (size_t)(row0 + t) * CDIM;
                xv[j] = f2b(s2f(xr[hh * HD + p]) * wst[t]);
                bv[j] = xr[DI + p];
            }
            *reinterpret_cast<short8*>(&XTw[p * 72 + t0]) = xv;
            *reinterpret_cast<short8*>(&BT[p * 72 + t0]) = bv;
        }
    }
    __syncthreads();

    int lane = tid & 63;
    int m = lane & 15;
    int kq = (lane >> 4) * 8;
    int w = tid >> 6;
    int a_off = (w * 16 + m) * 72 + kq;
    float4v acc[4];
    acc[0] = (float4v)0.f; acc[1] = (float4v)0.f; acc[2] = (float4v)0.f; acc[3] = (float4v)0.f;
    short8 a0 = *reinterpret_cast<const short8*>(&XTw[a_off]);
    short8 a1 = *reinterpret_cast<const short8*>(&XTw[a_off + 32]);
    #pragma unroll
    for (int nt = 0; nt < 4; nt++) {
        int bo = (nt * 16 + m) * 72 + kq;
        short8 b0 = *reinterpret_cast<const short8*>(&BT[bo]);
        short8 b1 = *reinterpret_cast<const short8*>(&BT[bo + 32]);
        acc[nt] = __builtin_amdgcn_mfma_f32_16x16x32_bf16(a0, b0, acc[nt], 0, 0, 0);
        acc[nt] = __builtin_amdgcn_mfma_f32_16x16x32_bf16(a1, b1, acc[nt], 0, 0, 0);
    }
    short* Sp = Slocb + (size_t)bid * (HD * DST);
    int tq = (lane >> 4) * 4;
    #pragma unroll
    for (int nt = 0; nt < 4; nt++) {
        #pragma unroll
        for (int r = 0; r < 4; r++) {
            int p = w * 16 + tq + r;
            int n = nt * 16 + m;
            Sp[p * DST + n] = f2b(acc[nt][r]);   // [p][n] bf16
        }
    }
}

// ---------------- chunk C (MFMA) + fused inter-chunk recurrence: outputs -> y bf16 ----------------
__global__ __launch_bounds__(256) void chunk_out_mfma(const short* __restrict__ xcb,
                                                      const float* __restrict__ dtb,
                                                      const float* __restrict__ A_log,
                                                      const float* __restrict__ Dpw,
                                                      const short* __restrict__ Slocb,
                                                      const float* __restrict__ decay,
                                                      short* __restrict__ ybb, int layer) {
    __shared__ short Cb[64 * 72];    // [t][n]
    __shared__ short Bb[64 * 72];    // [s][n], later M[t][s]
    __shared__ short XT[64 * 72];    // [p][t]
    __shared__ short HT[64 * 72];    // [p][n]
    __shared__ float Ls[64], dts[64];
    int bid = blockIdx.x;
    int c  = bid & (NCHUNK - 1);
    int hh = (bid >> 4) & (NH - 1);
    int b  = bid >> 6;
    int tid = threadIdx.x;
    int row0 = b * SEQ + c * CHUNK;
    int bh0 = bid & ~(NCHUNK - 1);
    float A = -expf(A_log[layer * NH + hh]);
    float Dph = Dpw[layer * NH + hh];

    if (tid < CHUNK) {
        float dtv = dtb[(size_t)(row0 + tid) * NH + hh];
        float l = dtv * A;
        #pragma unroll
        for (int o = 1; o < 64; o <<= 1) { float v = __shfl_up(l, o); if (tid >= o) l += v; }
        Ls[tid] = l;
        dts[tid] = dtv;
    }
    {   // fused inter-chunk recurrence: hstart in registers
        float hreg[16];
        #pragma unroll
        for (int k = 0; k < 16; k++) hreg[k] = 0.f;
        for (int j = 0; j < c; j++) {
            float d = decay[bh0 + j];
            const short* Sp = Slocb + (size_t)(bh0 + j) * (HD * DST) + tid * 16;
            short8 s0 = *reinterpret_cast<const short8*>(Sp);
            short8 s1 = *reinterpret_cast<const short8*>(Sp + 8);
            #pragma unroll
            for (int k = 0; k < 8; k++) {
                hreg[k]     = d * hreg[k]     + s2f(s0[k]);
                hreg[8 + k] = d * hreg[8 + k] + s2f(s1[k]);
            }
        }
        int p = tid >> 2;
        int n0 = (tid & 3) * 16;
        short8 h0, h1;
        #pragma unroll
        for (int k = 0; k < 8; k++) { h0[k] = f2b(hreg[k]); h1[k] = f2b(hreg[8 + k]); }
        *reinterpret_cast<short8*>(&HT[p * 72 + n0]) = h0;
        *reinterpret_cast<short8*>(&HT[p * 72 + n0 + 8]) = h1;
    }
    {
        int p = tid & 63;
        int tb0 = tid >> 6;
        #pragma unroll
        for (int i = 0; i < 2; i++) {
            int t0 = (tb0 + i * 4) * 8;
            short8 xv;
            #pragma unroll
            for (int j = 0; j < 8; j++)
                xv[j] = xcb[(size_t)(row0 + t0 + j) * CDIM + hh * HD + p];
            *reinterpret_cast<short8*>(&XT[p * 72 + t0]) = xv;
        }
    }
    #pragma unroll
    for (int i = 0; i < 2; i++) {
        int idx = tid + i * 256;
        int t = idx >> 3, cb = (idx & 7) * 8;
        const short* xr = xcb + (size_t)(row0 + t) * CDIM;
        *reinterpret_cast<short8*>(&Bb[t * 72 + cb]) =
            *reinterpret_cast<const short8*>(&xr[DI + cb]);
        *reinterpret_cast<short8*>(&Cb[t * 72 + cb]) =
            *reinterpret_cast<const short8*>(&xr[DI + DST + cb]);
    }
    __syncthreads();

    int lane = tid & 63;
    int m = lane & 15;
    int kq = (lane >> 4) * 8;
    int w = tid >> 6;
    int tq = (lane >> 4) * 4;
    int a_off = (w * 16 + m) * 72 + kq;

    short8 ca0 = *reinterpret_cast<const short8*>(&Cb[a_off]);
    short8 ca1 = *reinterpret_cast<const short8*>(&Cb[a_off + 32]);

    float4v g[4], ir[4];
    #pragma unroll
    for (int i = 0; i < 4; i++) { g[i] = (float4v)0.f; ir[i] = (float4v)0.f; }
    #pragma unroll
    for (int st = 0; st < 4; st++) {
        int bo = (st * 16 + m) * 72 + kq;
        short8 b0 = *reinterpret_cast<const short8*>(&Bb[bo]);
        short8 b1 = *reinterpret_cast<const short8*>(&Bb[bo + 32]);
        g[st] = __builtin_amdgcn_mfma_f32_16x16x32_bf16(ca0, b0, g[st], 0, 0, 0);
        g[st] = __builtin_amdgcn_mfma_f32_16x16x32_bf16(ca1, b1, g[st], 0, 0, 0);
        short8 h0 = *reinterpret_cast<const short8*>(&HT[bo]);
        short8 h1 = *reinterpret_cast<const short8*>(&HT[bo + 32]);
        ir[st] = __builtin_amdgcn_mfma_f32_16x16x32_bf16(ca0, h0, ir[st], 0, 0, 0);
        ir[st] = __builtin_amdgcn_mfma_f32_16x16x32_bf16(ca1, h1, ir[st], 0, 0, 0);
    }
    __syncthreads();
    #pragma unroll
    for (int st = 0; st < 4; st++) {
        #pragma unroll
        for (int r = 0; r < 4; r++) {
            int t = w * 16 + tq + r;
            int s = st * 16 + m;
            float mv = 0.f;
            if (s <= t) mv = g[st][r] * expf(Ls[t] - Ls[s]) * dts[s];
            Bb[t * 72 + s] = f2b(mv);
        }
    }
    __syncthreads();
    float4v yi[4];
    #pragma unroll
    for (int i = 0; i < 4; i++) yi[i] = (float4v)0.f;
    short8 ma0 = *reinterpret_cast<const short8*>(&Bb[a_off]);
    short8 ma1 = *reinterpret_cast<const short8*>(&Bb[a_off + 32]);
    #pragma unroll
    for (int pt = 0; pt < 4; pt++) {
        int bo = (pt * 16 + m) * 72 + kq;
        short8 x0 = *reinterpret_cast<const short8*>(&XT[bo]);
        short8 x1 = *reinterpret_cast<const short8*>(&XT[bo + 32]);
        yi[pt] = __builtin_amdgcn_mfma_f32_16x16x32_bf16(ma0, x0, yi[pt], 0, 0, 0);
        yi[pt] = __builtin_amdgcn_mfma_f32_16x16x32_bf16(ma1, x1, yi[pt], 0, 0, 0);
    }
    #pragma unroll
    for (int r = 0; r < 4; r++) {
        int t = w * 16 + tq + r;
        float et = expf(Ls[t]);
        short* yr = ybb + (size_t)(row0 + t) * DI + hh * HD;
        #pragma unroll
        for (int pt = 0; pt < 4; pt++) {
            int p = pt * 16 + m;
            float xv = s2f(XT[p * 72 + t]);
            yr[p] = f2b(yi[pt][r] + et * ir[pt][r] + Dph * xv);
        }
    }
}

// ---------------- out_proj + gate/RMSNorm + residual (+ LN for layer0, + fc2 for layer1) ----------------
__global__ __launch_bounds__(512) void outproj_gate_mfma(const short* __restrict__ ybb,
                                                         const short* __restrict__ zb,
                                                         const float* __restrict__ rmsw,
                                                         const short* __restrict__ wb,
                                                         const float* __restrict__ lnw2,
                                                         const float* __restrict__ lnb2,
                                                         float* __restrict__ h,
                                                         short* __restrict__ hnb,
                                                         const float* __restrict__ fc2_b1,
                                                         const float* __restrict__ fc2_W2,
                                                         const float* __restrict__ fc2_b2,
                                                         float* __restrict__ outp,
                                                         int layer, int do_fc2) {
    __shared__ __align__(16) char smem[36864];
    short* As = (short*)smem;                  // [64][72] main GEMM A
    short* Bt = (short*)(smem + 9216);         // [128][72] main GEMM B
    float* hs = (float*)smem;                  // [64][133] overlay
    short* As2 = (short*)smem;                 // [64][136] fc2 A overlay
    short* Bt2 = (short*)(smem + 17408);       // [128][72] fc2 B overlay
    float* h2s = (float*)smem;                 // [64][132] overlay
    __shared__ float rs_s[64];
    __shared__ float w2s[768];
    GEMM_PROLOGUE();
    int row0 = blockIdx.x * 64;
    const short* wt = wb + WB_OUT + (size_t)layer * 32768;
    if (do_fc2)
        for (int i = tid; i < 768; i += 512) w2s[i] = fc2_W2[i];
    {   // RMS stats on v = y*silu(z): 8 threads/row, 32 cols each
        int r = tid >> 3, j = tid & 7;
        const short8* yr = (const short8*)(ybb + (size_t)(row0 + r) * DI + j * 32);
        const short8* zr = (const short8*)(zb + (size_t)(row0 + r) * DI + j * 32);
        float s2 = 0.f;
        #pragma unroll
        for (int i = 0; i < 4; i++) {
            short8 yv = yr[i];
            short8 zv = zr[i];
            #pragma unroll
            for (int q = 0; q < 8; q++) {
                float v = s2f(yv[q]) * silu(s2f(zv[q]));
                s2 += v * v;
            }
        }
        #pragma unroll
        for (int o = 1; o < 8; o <<= 1) s2 += __shfl_xor(s2, o);
        if (j == 0) rs_s[r] = rsqrtf(s2 * (1.f / 256.f) + 1e-5f);
    }
    __syncthreads();
    for (int kt = 0; kt < 4; kt++) {
        int k0 = kt * 64;
        if (kt) __syncthreads();
        {
            int k = k0 + ak;
            short8 yv = *(const short8*)(ybb + (size_t)(row0 + ar) * DI + k);
            short8 zv = *(const short8*)(zb + (size_t)(row0 + ar) * DI + k);
            float4 w0 = *(const float4*)(rmsw + layer * DI + k);
            float4 w1 = *(const float4*)(rmsw + layer * DI + k + 4);
            float rs = rs_s[ar];
            short8 av;
            av[0] = f2b(s2f(yv[0]) * silu(s2f(zv[0])) * rs * w0.x);
            av[1] = f2b(s2f(yv[1]) * silu(s2f(zv[1])) * rs * w0.y);
            av[2] = f2b(s2f(yv[2]) * silu(s2f(zv[2])) * rs * w0.z);
            av[3] = f2b(s2f(yv[3]) * silu(s2f(zv[3])) * rs * w0.w);
            av[4] = f2b(s2f(yv[4]) * silu(s2f(zv[4])) * rs * w1.x);
            av[5] = f2b(s2f(yv[5]) * silu(s2f(zv[5])) * rs * w1.y);
            av[6] = f2b(s2f(yv[6]) * silu(s2f(zv[6])) * rs * w1.z);
            av[7] = f2b(s2f(yv[7]) * silu(s2f(zv[7])) * rs * w1.w);
            *reinterpret_cast<short8*>(&As[ar * 72 + ak]) = av;
        }
        GEMM_STAGE_B(wt, 256, k0);
        __syncthreads();
        GEMM_COMPUTE_TILE();
    }
    __syncthreads();   // done with As/Bt; reuse as hs
    #pragma unroll
    for (int nt = 0; nt < 4; nt++) {
        int col = ngrp * 64 + nt * 16 + m;
        #pragma unroll
        for (int r = 0; r < 4; r++) {
            int rr = mrow + (lane >> 4) * 4 + r;
            hs[rr * 133 + col] = acc[nt][r];
        }
    }
    __syncthreads();
    // residual add (8 threads/row, 16 cols each) -> vals registers
    int er = tid >> 3, ej = tid & 7;
    int erow = row0 + er;
    float vals[16];
    {
        const float* hsrc = h + (size_t)erow * DM + ej * 16;
        float s1 = 0.f, s2 = 0.f;
        #pragma unroll
        for (int i = 0; i < 4; i++) {
            float4 ho = *(const float4*)(hsrc + i * 4);
            float v0 = ho.x + hs[er * 133 + ej * 16 + i * 4];
            float v1 = ho.y + hs[er * 133 + ej * 16 + i * 4 + 1];
            float v2 = ho.z + hs[er * 133 + ej * 16 + i * 4 + 2];
            float v3 = ho.w + hs[er * 133 + ej * 16 + i * 4 + 3];
            vals[i*4] = v0; vals[i*4+1] = v1; vals[i*4+2] = v2; vals[i*4+3] = v3;
            s1 += v0 + v1 + v2 + v3;
            s2 += v0*v0 + v1*v1 + v2*v2 + v3*v3;
        }
        if (!do_fc2) {
            #pragma unroll
            for (int o = 1; o < 8; o <<= 1) { s1 += __shfl_xor(s1, o); s2 += __shfl_xor(s2, o); }
            float* hdst = h + (size_t)erow * DM + ej * 16;
            #pragma unroll
            for (int i = 0; i < 4; i++)
                *(float4*)(hdst + i * 4) = make_float4(vals[i*4], vals[i*4+1], vals[i*4+2], vals[i*4+3]);
            float mu = s1 * (1.f / 128.f);
            float rs = rsqrtf(s2 * (1.f / 128.f) - mu * mu + 1e-5f);
            const float* lw = lnw2 + ej * 16;
            const float* lb = lnb2 + ej * 16;
            short8 a0, a1;
            #pragma unroll
            for (int i = 0; i < 8; i++) {
                a0[i] = f2b((vals[i] - mu) * rs * lw[i] + lb[i]);
                a1[i] = f2b((vals[8 + i] - mu) * rs * lw[8 + i] + lb[8 + i]);
            }
            short* hndst = hnb + (size_t)erow * DM + ej * 16;
            *reinterpret_cast<short8*>(hndst) = a0;
            *reinterpret_cast<short8*>(hndst + 8) = a1;
        }
    }
    if (!do_fc2) return;

    // ---- fused fc2a + fc2b (layer 1 only): vals -> As2 bf16, GEMM vs W1t, leaky, then 128->6 ----
    __syncthreads();   // hs reads done by all threads; safe to overwrite with As2
    {
        short8 a0p, a1p;
        #pragma unroll
        for (int i = 0; i < 8; i++) { a0p[i] = f2b(vals[i]); a1p[i] = f2b(vals[8 + i]); }
        *reinterpret_cast<short8*>(&As2[er * 136 + ej * 16]) = a0p;
        *reinterpret_cast<short8*>(&As2[er * 136 + ej * 16 + 8]) = a1p;
    }
    const short* wtf = wb + WB_FC2;
    float4v acc2[4];
    acc2[0] = (float4v)0.f; acc2[1] = (float4v)0.f; acc2[2] = (float4v)0.f; acc2[3] = (float4v)0.f;
    for (int kt = 0; kt < 2; kt++) {
        int k0 = kt * 64;
        __syncthreads();
        #pragma unroll
        for (int i = 0; i < 2; i++) {
            int idx = tid + i * 512;
            int n = idx >> 3, kk = (idx & 7) * 8;
            *reinterpret_cast<short8*>(&Bt2[n * 72 + kk]) =
                *reinterpret_cast<const short8*>(&wtf[n * 128 + k0 + kk]);
        }
        __syncthreads();
        short8 a0 = *reinterpret_cast<const short8*>(&As2[(mrow + m) * 136 + k0 + kq]);
        short8 a1 = *reinterpret_cast<const short8*>(&As2[(mrow + m) * 136 + k0 + kq + 32]);
        #pragma unroll
        for (int nt = 0; nt < 4; nt++) {
            int bo = (ngrp * 64 + nt * 16 + m) * 72 + kq;
            short8 b0 = *reinterpret_cast<const short8*>(&Bt2[bo]);
            short8 b1 = *reinterpret_cast<const short8*>(&Bt2[bo + 32]);
            acc2[nt] = __builtin_amdgcn_mfma_f32_16x16x32_bf16(a0, b0, acc2[nt], 0, 0, 0);
            acc2[nt] = __builtin_amdgcn_mfma_f32_16x16x32_bf16(a1, b1, acc2[nt], 0, 0, 0);
        }
    }
    __syncthreads();   // all MFMA LDS reads done; overwrite with h2s
    #pragma unroll
    for (int nt = 0; nt < 4; nt++) {
        int col = ngrp * 64 + nt * 16 + m;
        float bv = fc2_b1[col];
        #pragma unroll
        for (int r = 0; r < 4; r++) {
            int rr = mrow + (lane >> 4) * 4 + r;
            float o = acc2[nt][r] + bv;
            h2s[rr * 132 + col] = (o > 0.f) ? o : 0.1f * o;
        }
    }
    __syncthreads();
    if (tid < 384) {
        int r = tid / 6, cc = tid % 6;
        float a2 = fc2_b2[cc];
        #pragma unroll 16
        for (int k = 0; k < 128; k++) a2 += h2s[r * 132 + k] * w2s[k * 6 + cc];
        outp[(size_t)(row0 + r) * 6 + cc] = a2;
    }
}

extern "C" void kernel_launch(void* const* d_in, const int* in_sizes, int n_in,
                              void* d_out, int out_size, void* d_ws, size_t ws_size,
                              hipStream_t stream) {
    const float* x       = (const float*)d_in[0];
    const float* fc1_W   = (const float*)d_in[1];
    const float* fc1_b   = (const float*)d_in[2];
    const float* ln_w    = (const float*)d_in[3];
    const float* ln_b    = (const float*)d_in[4];
    const float* in_W    = (const float*)d_in[5];
    const float* conv_w  = (const float*)d_in[6];
    const float* conv_b  = (const float*)d_in[7];
    const float* dt_bias = (const float*)d_in[8];
    const float* A_log   = (const float*)d_in[9];
    const float* Dp      = (const float*)d_in[10];
    const float* rms_w   = (const float*)d_in[11];
    const float* out_W   = (const float*)d_in[12];
    const float* fc2_W1  = (const float*)d_in[13];
    const float* fc2_b1  = (const float*)d_in[14];
    const float* fc2_W2  = (const float*)d_in[15];
    const float* fc2_b2  = (const float*)d_in[16];
    float* out = (float*)d_out;

    float* ws = (float*)d_ws;
    float* h     = ws;                            // NROWS*DM f32
    float* dtb   = h     + (size_t)NROWS * DM;    // NROWS*NH f32
    float* decay = dtb   + (size_t)NROWS * NH;    // 1024 f32
    short* sbase = (short*)(decay + 1024);
    short* hnb   = sbase;                          // NROWS*DM sh
    short* zb    = hnb   + (size_t)NROWS * DM;     // NROWS*DI sh
    short* xbc   = zb    + (size_t)NROWS * DI;     // NROWS*CDIM sh
    short* xcb   = xbc   + (size_t)NROWS * CDIM;   // NROWS*CDIM sh
    short* ybb   = xcb   + (size_t)NROWS * CDIM;   // NROWS*DI sh
    short* Slocb = ybb   + (size_t)NROWS * DI;     // 1024*4096 sh
    short* wb    = Slocb + (size_t)BATCH*NH*NCHUNK*HD*DST;

    prep_weights<<<1348, 256, 0, stream>>>(fc1_W, in_W, out_W, fc2_W1, wb);
    fc1_mfma<<<NROWS / 32, 512, 0, stream>>>(x, wb + WB_FC1, fc1_b, ln_w, ln_b, h, hnb);

    for (int layer = 0; layer < 2; layer++) {
        inproj_mfma<<<dim3(NROWS / 64, 6), 512, 0, stream>>>(hnb, wb, zb, xbc, dtb,
                                                             dt_bias, layer);
        conv_kernel<<<NROWS / 4, CDIM, 0, stream>>>(xbc, conv_w, conv_b, xcb, layer);
        chunk_state_mfma<<<BATCH*NH*NCHUNK, 256, 0, stream>>>(xcb, dtb, A_log, Slocb, decay, layer);
        chunk_out_mfma<<<BATCH*NH*NCHUNK, 256, 0, stream>>>(xcb, dtb, A_log, Dp, Slocb, decay,
                                                            ybb, layer);
        outproj_gate_mfma<<<NROWS / 64, 512, 0, stream>>>(ybb, zb, rms_w, wb,
                                                          ln_w + DM, ln_b + DM, h, hnb,
                                                          fc2_b1, fc2_W2, fc2_b2, out,
                                                          layer, layer == 1 ? 1 : 0);
    }
}